// Round 5
// baseline (439.797 us; speedup 1.0000x reference)
//
#include <hip/hip_runtime.h>

#define NN 100000     // nodes
#define NE 1600000    // edges
#define NGR 512       // graphs
#define KF 128        // IN_F == H1
#define H2F 256
#define NGRP 16
#define NFAM 10

#define CH 128                          // nodes per chunk
#define NCHUNK ((NN + CH - 1) / CH)     // 782
#define PT 6656                         // edges per histogram tile
#define NT ((NE + PT - 1) / PT)         // 241
#define PREPB_BLKS 64                   // 128*128/256

typedef __attribute__((ext_vector_type(8))) short short8;
typedef __attribute__((ext_vector_type(4))) float floatx4;
typedef __attribute__((ext_vector_type(2))) float floatx2;
typedef __attribute__((ext_vector_type(2))) unsigned uintx2;

__device__ __forceinline__ unsigned short f2bf(float f) {
  unsigned u = __float_as_uint(f);
  unsigned r = (u + 0x7fff + ((u >> 16) & 1)) >> 16;
  return (unsigned short)r;
}
__device__ __forceinline__ float2 bf2f(unsigned u) {
  float2 r;
  r.x = __uint_as_float(u << 16);
  r.y = __uint_as_float(u & 0xffff0000u);
  return r;
}
// fp8 e4m3 pair (features t, t+64) <-> floats via gfx950 HW converters
__device__ __forceinline__ unsigned short pk_fp8(float a, float b) {
  return (unsigned short)__builtin_amdgcn_cvt_pk_fp8_f32(a, b, 0, false);
}
__device__ __forceinline__ floatx2 unpk_fp8(unsigned short u) {
  return __builtin_amdgcn_cvt_pk_f32_fp8((int)u, false);
}

// ---------------- merged: chunk hist -> tot | node degree hist | W1 swizzle ----------------

__global__ __launch_bounds__(256) void k_histprep(const int* __restrict__ ei,
                                                  int* __restrict__ tot,
                                                  int* __restrict__ nodedeg,
                                                  const float* __restrict__ W,
                                                  unsigned short* __restrict__ Bp) {
  __shared__ int lh[NCHUNK];
  int tid = threadIdx.x;
  if (blockIdx.x >= NT) {
    int idx = (blockIdx.x - NT) * 256 + tid;
    int j = idx & 7;
    int l = (idx >> 3) & 63;
    int rest = idx >> 9;
    int nc = rest & 7;
    int kc = rest >> 3;
    int k = kc * 32 + (l >> 4) * 8 + j;
    int nn = nc * 16 + (l & 15);
    Bp[idx] = f2bf(W[k * KF + nn]);
    return;
  }
  for (int g = tid; g < NCHUNK; g += 256) lh[g] = 0;
  __syncthreads();
  int base = blockIdx.x * PT;
  int nv = min(PT, NE - base);
  for (int i = tid; i < nv; i += 256) {
    int d = ei[NE + base + i];
    atomicAdd(&lh[d >> 7], 1);
    atomicAdd(&nodedeg[d], 1);
  }
  __syncthreads();
  for (int g = tid; g < NCHUNK; g += 256) {
    int v = lh[g];
    if (v) atomicAdd(&tot[g], v);
  }
}

// ---------------- exclusive scan tot -> cbase ----------------

__global__ __launch_bounds__(256) void k_scantot(const int* __restrict__ tot,
                                                 int* __restrict__ cbase) {
  __shared__ int ssc[256];
  int tid = threadIdx.x;
  int v4[4]; int loc = 0;
#pragma unroll
  for (int j = 0; j < 4; ++j) {
    int idx = tid * 4 + j;
    v4[j] = (idx < NCHUNK) ? tot[idx] : 0;
    loc += v4[j];
  }
  ssc[tid] = loc;
  __syncthreads();
  for (int off = 1; off < 256; off <<= 1) {
    int val = (tid >= off) ? ssc[tid - off] : 0;
    __syncthreads();
    ssc[tid] += val;
    __syncthreads();
  }
  int excl = ssc[tid] - loc;
#pragma unroll
  for (int j = 0; j < 4; ++j) {
    int idx = tid * 4 + j;
    if (idx < NCHUNK) cbase[idx] = excl;
    excl += v4[j];
  }
  if (tid == 255) cbase[NCHUNK] = excl;  // == NE
}

// ---------------- per-chunk node-degree scan -> rowptr/cursor/dinv ----------------

__global__ __launch_bounds__(CH) void k_nodescan(const int* __restrict__ nodedeg,
                                                 const int* __restrict__ cbase,
                                                 int* __restrict__ rowptr,
                                                 int* __restrict__ cursor,
                                                 float* __restrict__ dinv) {
  __shared__ int sc[CH];
  const int c = blockIdx.x, tid = threadIdx.x;
  const int node = c * CH + tid;
  const int deg = (node < NN) ? nodedeg[node] : 0;
  sc[tid] = deg;
  __syncthreads();
  for (int off = 1; off < CH; off <<= 1) {
    int val = (tid >= off) ? sc[tid - off] : 0;
    __syncthreads();
    sc[tid] += val;
    __syncthreads();
  }
  const int excl = sc[tid] - deg + cbase[c];
  if (node < NN) {
    rowptr[node] = excl;
    cursor[node] = excl;
    dinv[node] = rsqrtf((float)(deg + 1));  // in-degree + self loop
  }
  if (c == NCHUNK - 1 && tid == 0) rowptr[NN] = NE;
}

// ---------------- direct edge scatter: esrc[atomic pos] = src ----------------

__global__ __launch_bounds__(256) void k_escatter(const int* __restrict__ ei,
                                                  int* __restrict__ cursor,
                                                  int* __restrict__ esrc) {
  const int i = blockIdx.x * 256 + threadIdx.x;
  if (i >= NE) return;
  const int s = ei[i];
  const int d = ei[NE + i];
  const int pos = atomicAdd(&cursor[d], 1);
  esrc[pos] = s;
}

// ---------------- MFMA GEMM1: xw1'[n] = dinv[n]*(x[n] @ W1), fp8 out ----------------
// fp8 row layout: ushort at pos t holds features (t, t+64); in C-layout these are
// cols nc*16+m and (nc+4)*16+m -- SAME lane, so packing is lane-local.

__global__ __launch_bounds__(256) void k_gemm_mfma(const float* __restrict__ A,
                                                   const unsigned short* __restrict__ Bp,
                                                   const float* __restrict__ dinv,
                                                   unsigned short* __restrict__ C) {
  constexpr int K = 128;
  constexpr int NCH = KF / 16;
  const int wv = blockIdx.x * 4 + (threadIdx.x >> 6);
  const int row0 = wv * 16;
  if (row0 >= NN) return;  // 100000 % 16 == 0
  const int lane = threadIdx.x & 63;
  const int m = lane & 15;
  const int q = lane >> 4;

  floatx4 acc[NCH];
#pragma unroll
  for (int i = 0; i < NCH; ++i) acc[i] = (floatx4){0.f, 0.f, 0.f, 0.f};

  const int arow = row0 + m;
#pragma unroll
  for (int kc = 0; kc < 4; ++kc) {
    const float* ap = A + (size_t)arow * K + kc * 32 + q * 8;
    float4 f0 = *(const float4*)ap;
    float4 f1 = *(const float4*)(ap + 4);
    short8 af;
    af[0] = (short)f2bf(f0.x); af[1] = (short)f2bf(f0.y);
    af[2] = (short)f2bf(f0.z); af[3] = (short)f2bf(f0.w);
    af[4] = (short)f2bf(f1.x); af[5] = (short)f2bf(f1.y);
    af[6] = (short)f2bf(f1.z); af[7] = (short)f2bf(f1.w);
    const unsigned short* bp = Bp + (size_t)kc * NCH * 512;
#pragma unroll
    for (int nc = 0; nc < NCH; ++nc) {
      short8 bfr = *(const short8*)(bp + (size_t)nc * 512 + lane * 8);
      acc[nc] = __builtin_amdgcn_mfma_f32_16x16x32_bf16(af, bfr, acc[nc], 0, 0, 0);
    }
  }

  float ds[4];
#pragma unroll
  for (int r = 0; r < 4; ++r) ds[r] = dinv[row0 + q * 4 + r];
#pragma unroll
  for (int nc = 0; nc < 4; ++nc) {
#pragma unroll
    for (int r = 0; r < 4; ++r) {
      int row = row0 + q * 4 + r;
      C[(size_t)row * 64 + nc * 16 + m] =
          pk_fp8(acc[nc][r] * ds[r], acc[nc + 4][r] * ds[r]);
    }
  }
}

// ---------------- aggregation: paired-edge dword gathers (round-1 form) ----------------
// Row = 128 B = 32 dwords. Lanes 0-31 process even-offset edges, lanes 32-63
// odd-offset edges; each lane loads one dword = fp8 pairs for features
// (2u, 2u+64) and (2u+1, 2u+65). Halves fold via __shfl_down(.,32).
// agg1: h1'[n] = dinv[n]*relu( dinv[n]*(sum + self) + b1 ), fp8 out
// agg2: out[n] = dinv[n]*(sum + self), bf16 out (uint: low=feat t, high=feat t+64)

template <bool FIRST>
__global__ __launch_bounds__(128) void k_agg(const unsigned short* __restrict__ p,
                                             const float* __restrict__ bias,
                                             const int* __restrict__ rowptr,
                                             const int* __restrict__ esrc,
                                             const float* __restrict__ dinv,
                                             void* __restrict__ outp) {
  const int n = blockIdx.x * 2 + (threadIdx.x >> 6);
  const int t = threadIdx.x & 63;
  const int u = t & 31;      // dword index within the 32-dword row
  const int half = t >> 5;   // which edge of the pair this lane serves
  const unsigned* __restrict__ prow = (const unsigned*)p;

  // accumulators for features 2u, 2u+64, 2u+1, 2u+65
  float a0 = 0.f, a1 = 0.f, a2 = 0.f, a3 = 0.f;

  if (half == 0) {  // self term (prescaled input), added once
    unsigned v = prow[((unsigned)n << 5) + u];
    floatx2 lo = unpk_fp8((unsigned short)(v & 0xffffu));
    floatx2 hi = unpk_fp8((unsigned short)(v >> 16));
    a0 = lo.x; a1 = lo.y; a2 = hi.x; a3 = hi.y;
  }

  const int r0 = rowptr[n];
  const int r1 = rowptr[n + 1];
  int i = r0;

#define PAIR_TIER(NP)                                                  \
  for (; i + 2 * (NP) <= r1; i += 2 * (NP)) {                          \
    const int ib = i + half;                                           \
    unsigned s[NP];                                                    \
    _Pragma("unroll") for (int j = 0; j < (NP); ++j)                   \
        s[j] = (unsigned)esrc[ib + 2 * j];                             \
    unsigned v[NP];                                                    \
    _Pragma("unroll") for (int j = 0; j < (NP); ++j)                   \
        v[j] = prow[(s[j] << 5) + u];                                  \
    _Pragma("unroll") for (int j = 0; j < (NP); ++j) {                 \
      floatx2 lo = unpk_fp8((unsigned short)(v[j] & 0xffffu));         \
      floatx2 hi = unpk_fp8((unsigned short)(v[j] >> 16));             \
      a0 += lo.x; a1 += lo.y; a2 += hi.x; a3 += hi.y;                  \
    }                                                                  \
  }

  PAIR_TIER(8)   // 16 edges / iter
  PAIR_TIER(4)   // 8
  PAIR_TIER(2)   // 4
  PAIR_TIER(1)   // 2
#undef PAIR_TIER

  if (i < r1 && half == 0) {  // odd leftover edge: half 0 only
    unsigned s = (unsigned)esrc[i];
    unsigned v = prow[(s << 5) + u];
    floatx2 lo = unpk_fp8((unsigned short)(v & 0xffffu));
    floatx2 hi = unpk_fp8((unsigned short)(v >> 16));
    a0 += lo.x; a1 += lo.y; a2 += hi.x; a3 += hi.y;
  }

  // fold half-wave partials: lane u gets lane u+32's sums
  a0 += __shfl_down(a0, 32, 64);
  a1 += __shfl_down(a1, 32, 64);
  a2 += __shfl_down(a2, 32, 64);
  a3 += __shfl_down(a3, 32, 64);

  if (half == 0) {
    const float dn = dinv[n];
    if (FIRST) {
      float2 blo = *(const float2*)(bias + 2 * u);       // bias[2u], bias[2u+1]
      float2 bhi = *(const float2*)(bias + 64 + 2 * u);  // bias[2u+64], bias[2u+65]
      float x0 = fmaxf(fmaf(dn, a0, blo.x), 0.f) * dn;   // feat 2u
      float x1 = fmaxf(fmaf(dn, a1, bhi.x), 0.f) * dn;   // feat 2u+64
      float x2 = fmaxf(fmaf(dn, a2, blo.y), 0.f) * dn;   // feat 2u+1
      float x3 = fmaxf(fmaf(dn, a3, bhi.y), 0.f) * dn;   // feat 2u+65
      unsigned lo = pk_fp8(x0, x1);
      unsigned hi = pk_fp8(x2, x3);
      ((unsigned*)outp)[((unsigned)n << 5) + u] = lo | (hi << 16);
    } else {
      float x0 = a0 * dn, x1 = a1 * dn, x2 = a2 * dn, x3 = a3 * dn;
      uintx2 w;
      w.x = (unsigned)f2bf(x0) | ((unsigned)f2bf(x1) << 16);
      w.y = (unsigned)f2bf(x2) | ((unsigned)f2bf(x3) << 16);
      ((uintx2*)outp)[((unsigned)n << 5) + u] = w;
    }
  }
}

// ---------------- fused mean-pool + mini-GEMM + heads (one block per graph) ----------------
// agg2 bf16 rows: uint at pos t = features (t, t+64)

__global__ __launch_bounds__(256) void k_poolheads(const unsigned* __restrict__ hp,
                                                   const int* __restrict__ batch,
                                                   const float* __restrict__ W2,
                                                   const float* __restrict__ b2,
                                                   const float* __restrict__ Wg,
                                                   const float* __restrict__ bg,
                                                   const float* __restrict__ Wf,
                                                   const float* __restrict__ bfb,
                                                   float* __restrict__ out) {
  __shared__ float sh[4][128];
  __shared__ float pr[KF];
  __shared__ float p[H2F];
  __shared__ int bnd[2];
  const int g = blockIdx.x;
  const int tid = threadIdx.x;
  if (tid < 2) {
    int target = g + tid;
    int lo = 0, hi = NN;
    while (lo < hi) { int mid = (lo + hi) >> 1; if (batch[mid] < target) lo = mid + 1; else hi = mid; }
    bnd[tid] = lo;
  }
  __syncthreads();
  const int start = bnd[0], end = bnd[1];
  const int t = tid & 63, wv = tid >> 6;

  float sx = 0.f, sy = 0.f;
  int n = start + wv;
  for (; n + 12 < end; n += 16) {
    unsigned u0 = hp[(size_t)n * 64 + t];
    unsigned u1 = hp[(size_t)(n + 4) * 64 + t];
    unsigned u2 = hp[(size_t)(n + 8) * 64 + t];
    unsigned u3 = hp[(size_t)(n + 12) * 64 + t];
    float2 f0 = bf2f(u0), f1 = bf2f(u1), f2 = bf2f(u2), f3 = bf2f(u3);
    sx += (f0.x + f1.x) + (f2.x + f3.x);
    sy += (f0.y + f1.y) + (f2.y + f3.y);
  }
  for (; n < end; n += 4) {
    float2 f = bf2f(hp[(size_t)n * 64 + t]);
    sx += f.x; sy += f.y;
  }
  sh[wv][2 * t] = sx;
  sh[wv][2 * t + 1] = sy;
  __syncthreads();
  if (wv == 0) {
    float vx = sh[0][2 * t] + sh[1][2 * t] + sh[2][2 * t] + sh[3][2 * t];
    float vy = sh[0][2 * t + 1] + sh[1][2 * t + 1] + sh[2][2 * t + 1] + sh[3][2 * t + 1];
    float c = fmaxf((float)(end - start), 1.f);
    pr[t] = vx / c;        // feature t
    pr[t + 64] = vy / c;   // feature t+64
  }
  __syncthreads();
  float acc = b2[tid];
#pragma unroll 8
  for (int d = 0; d < KF; ++d) acc = fmaf(pr[d], W2[d * H2F + tid], acc);
  p[tid] = acc;
  __syncthreads();
  if (tid < NGRP) {
    float a = bg[tid];
    for (int d = 0; d < H2F; ++d) a = fmaf(p[d], Wg[d * NGRP + tid], a);
    out[g * NGRP + tid] = a;
  } else if (tid >= 64 && tid < 64 + NGRP * NFAM) {
    int u = tid - 64;
    int gg = u / NFAM;
    int ff = u % NFAM;
    float a = bfb[gg * NFAM + ff];
    for (int d = 0; d < H2F; ++d) a = fmaf(p[d], Wf[(gg * H2F + d) * NFAM + ff], a);
    out[NGR * NGRP + (size_t)gg * NGR * NFAM + g * NFAM + ff] = a;
  }
}

// ---------------- launch ----------------

extern "C" void kernel_launch(void* const* d_in, const int* in_sizes, int n_in,
                              void* d_out, int out_size, void* d_ws, size_t ws_size,
                              hipStream_t stream) {
  const float* x    = (const float*)d_in[0];
  const int*   ei   = (const int*)d_in[1];
  const int*   batch= (const int*)d_in[2];
  const float* W1   = (const float*)d_in[3];
  const float* b1   = (const float*)d_in[4];
  const float* W2   = (const float*)d_in[5];
  const float* b2   = (const float*)d_in[6];
  const float* Wg   = (const float*)d_in[7];
  const float* bg   = (const float*)d_in[8];
  const float* Wf   = (const float*)d_in[9];
  const float* bfb  = (const float*)d_in[10];
  float* out = (float*)d_out;

  char* w = (char*)d_ws;
  auto take = [&](size_t bytes) {
    char* p = w;
    w += (bytes + 255) & ~(size_t)255;
    return (void*)p;
  };
  int*   tot    = (int*)take((size_t)NCHUNK * 4);
  int*   nodedeg= (int*)take((size_t)NN * 4);      // contiguous after tot: one memset
  int*   cbase  = (int*)take((size_t)(NCHUNK + 1) * 4);
  int*   cursor = (int*)take((size_t)NN * 4);
  int*   esrc   = (int*)take((size_t)NE * 4);
  int*   rowptr = (int*)take((size_t)(NN + 1) * 4);
  float* dinv   = (float*)take((size_t)NN * 4);
  unsigned short* Bp1 = (unsigned short*)take((size_t)KF * KF * 2);
  unsigned short* xw1 = (unsigned short*)take((size_t)NN * 64 * 2);  // fp8 pairs
  unsigned short* h1  = (unsigned short*)take((size_t)NN * 64 * 2);  // fp8 pairs
  unsigned* agg2= (unsigned*)take((size_t)NN * KF * 2);

  // zero tot + nodedeg in one shot (they are adjacent in the workspace)
  size_t zbytes = (size_t)((char*)nodedeg - (char*)tot) + (size_t)NN * 4;
  hipMemsetAsync(tot, 0, zbytes, stream);

  k_histprep<<<NT + PREPB_BLKS, 256, 0, stream>>>(ei, tot, nodedeg, W1, Bp1);
  k_scantot<<<1, 256, 0, stream>>>(tot, cbase);
  k_nodescan<<<NCHUNK, CH, 0, stream>>>(nodedeg, cbase, rowptr, cursor, dinv);
  k_escatter<<<(NE + 255) / 256, 256, 0, stream>>>(ei, cursor, esrc);

  k_gemm_mfma<<<1563, 256, 0, stream>>>(x, Bp1, dinv, xw1);

  k_agg<true><<<NN / 2, 128, 0, stream>>>(xw1, b1, rowptr, esrc, dinv, h1);
  k_agg<false><<<NN / 2, 128, 0, stream>>>(h1, nullptr, rowptr, esrc, dinv, agg2);

  k_poolheads<<<NGR, 256, 0, stream>>>(agg2, batch, W2, b2, Wg, bg, Wf, bfb, out);
}

// Round 7
// 309.137 us; speedup vs baseline: 1.4227x; 1.4227x over previous
//
#include <hip/hip_runtime.h>

#define NN 100000     // nodes
#define NE 1600000    // edges
#define NGR 512       // graphs
#define KF 128        // IN_F == H1
#define H2F 256
#define NGRP 16
#define NFAM 10

#define CH 128                          // nodes per chunk
#define NCHUNK ((NN + CH - 1) / CH)     // 782
#define PT 3328                         // edges per partition tile (halved: 4 blocks/CU)
#define NT ((NE + PT - 1) / PT)         // 481
#define PREPB_BLKS 64                   // 128*128/256

typedef __attribute__((ext_vector_type(8))) short short8;
typedef __attribute__((ext_vector_type(4))) float floatx4;
typedef __attribute__((ext_vector_type(2))) float floatx2;
typedef __attribute__((ext_vector_type(2))) unsigned uintx2;

__device__ __forceinline__ unsigned short f2bf(float f) {
  unsigned u = __float_as_uint(f);
  unsigned r = (u + 0x7fff + ((u >> 16) & 1)) >> 16;
  return (unsigned short)r;
}
__device__ __forceinline__ float2 bf2f(unsigned u) {
  float2 r;
  r.x = __uint_as_float(u << 16);
  r.y = __uint_as_float(u & 0xffff0000u);
  return r;
}
// fp8 e4m3 pair (features t, t+64) <-> floats via gfx950 HW converters
__device__ __forceinline__ unsigned short pk_fp8(float a, float b) {
  return (unsigned short)__builtin_amdgcn_cvt_pk_fp8_f32(a, b, 0, false);
}
__device__ __forceinline__ floatx2 unpk_fp8(unsigned short u) {
  return __builtin_amdgcn_cvt_pk_f32_fp8((int)u, false);
}

// ---------------- merged: per-tile chunk histogram -> global tot  |  W1 swizzle ----------------

__global__ __launch_bounds__(256) void k_histprep(const int* __restrict__ ei,
                                                  int* __restrict__ tot,
                                                  const float* __restrict__ W,
                                                  unsigned short* __restrict__ Bp) {
  __shared__ int lh[NCHUNK];
  int tid = threadIdx.x;
  if (blockIdx.x >= NT) {
    int idx = (blockIdx.x - NT) * 256 + tid;
    int j = idx & 7;
    int l = (idx >> 3) & 63;
    int rest = idx >> 9;
    int nc = rest & 7;
    int kc = rest >> 3;
    int k = kc * 32 + (l >> 4) * 8 + j;
    int nn = nc * 16 + (l & 15);
    Bp[idx] = f2bf(W[k * KF + nn]);
    return;
  }
  for (int g = tid; g < NCHUNK; g += 256) lh[g] = 0;
  __syncthreads();
  int base = blockIdx.x * PT;
  int nv = min(PT, NE - base);
  for (int i = tid; i < nv; i += 256) atomicAdd(&lh[ei[NE + base + i] >> 7], 1);
  __syncthreads();
  for (int g = tid; g < NCHUNK; g += 256) {
    int v = lh[g];
    if (v) atomicAdd(&tot[g], v);
  }
}

// ---------------- exclusive scan tot -> cbase; init cursor ----------------

__global__ __launch_bounds__(256) void k_scantot(const int* __restrict__ tot,
                                                 int* __restrict__ cbase,
                                                 int* __restrict__ cursor) {
  __shared__ int ssc[256];
  int tid = threadIdx.x;
  int v4[4]; int loc = 0;
#pragma unroll
  for (int j = 0; j < 4; ++j) {
    int idx = tid * 4 + j;
    v4[j] = (idx < NCHUNK) ? tot[idx] : 0;
    loc += v4[j];
  }
  ssc[tid] = loc;
  __syncthreads();
  for (int off = 1; off < 256; off <<= 1) {
    int val = (tid >= off) ? ssc[tid - off] : 0;
    __syncthreads();
    ssc[tid] += val;
    __syncthreads();
  }
  int excl = ssc[tid] - loc;
#pragma unroll
  for (int j = 0; j < 4; ++j) {
    int idx = tid * 4 + j;
    if (idx < NCHUNK) { cbase[idx] = excl; cursor[idx] = excl; }
    excl += v4[j];
  }
  if (tid == 255) cbase[NCHUNK] = excl;  // == NE
}

// ---------------- partition: LDS-staged, cursor-reserved per-chunk slices ----------------

__global__ __launch_bounds__(256) void k_pscatter(const int* __restrict__ ei,
                                                  int* __restrict__ cursor,
                                                  int2* __restrict__ erec) {
  __shared__ int2 stage[PT];
  __shared__ int lstart[NCHUNK];
  __shared__ int lrun[NCHUNK];
  __shared__ int gbase[NCHUNK];
  __shared__ int ssc[256];
  int t0 = blockIdx.x, tid = threadIdx.x;
  for (int g = tid; g < NCHUNK; g += 256) lrun[g] = 0;
  __syncthreads();
  int base = t0 * PT;
  int nv = min(PT, NE - base);
  for (int i = tid; i < nv; i += 256) atomicAdd(&lrun[ei[NE + base + i] >> 7], 1);
  __syncthreads();
  int v4[4]; int loc = 0;
#pragma unroll
  for (int j = 0; j < 4; ++j) {
    int idx = tid * 4 + j;
    v4[j] = (idx < NCHUNK) ? lrun[idx] : 0;
    loc += v4[j];
  }
  ssc[tid] = loc;
  __syncthreads();
  for (int off = 1; off < 256; off <<= 1) {
    int val = (tid >= off) ? ssc[tid - off] : 0;
    __syncthreads();
    ssc[tid] += val;
    __syncthreads();
  }
  int excl = ssc[tid] - loc;
#pragma unroll
  for (int j = 0; j < 4; ++j) {
    int idx = tid * 4 + j;
    if (idx < NCHUNK) lstart[idx] = excl;
    excl += v4[j];
  }
  __syncthreads();
  for (int g = tid; g < NCHUNK; g += 256) {
    int cnt = ((g + 1 < NCHUNK) ? lstart[g + 1] : nv) - lstart[g];
    gbase[g] = cnt ? atomicAdd(&cursor[g], cnt) : 0;
    lrun[g] = lstart[g];
  }
  __syncthreads();
  for (int i = tid; i < nv; i += 256) {
    int s = ei[base + i], d = ei[NE + base + i];
    int pos = atomicAdd(&lrun[d >> 7], 1);
    stage[pos] = make_int2(s, d);
  }
  __syncthreads();
  for (int j = tid; j < nv; j += 256) {
    int2 r = stage[j];
    int g = r.y >> 7;
    erec[gbase[g] + (j - lstart[g])] = r;
  }
}

// ---------------- per-chunk counting sort into packed per-node runs (+dinv) ----------------

__global__ __launch_bounds__(256) void k_sort(const int2* __restrict__ erec,
                                              const int* __restrict__ cbase,
                                              int* __restrict__ esrc,
                                              int* __restrict__ rowptr,
                                              float* __restrict__ dinv) {
  __shared__ int hist[CH];
  __shared__ int lrun[CH];
  __shared__ int sc[256];
  const int c = blockIdx.x, tid = threadIdx.x;
  const int e0 = cbase[c], e1 = cbase[c + 1];
  const int nv = e1 - e0;
  if (tid < CH) hist[tid] = 0;
  __syncthreads();
  for (int i = tid; i < nv; i += 256) atomicAdd(&hist[erec[e0 + i].y & (CH - 1)], 1);
  __syncthreads();
  int deg = (tid < CH) ? hist[tid] : 0;
  sc[tid] = deg;
  __syncthreads();
  for (int off = 1; off < 256; off <<= 1) {
    int val = (tid >= off) ? sc[tid - off] : 0;
    __syncthreads();
    sc[tid] += val;
    __syncthreads();
  }
  int excl = sc[tid] - deg;
  int node = c * CH + tid;
  if (tid < CH) {
    lrun[tid] = excl;
    if (node < NN) {
      rowptr[node] = e0 + excl;
      dinv[node] = rsqrtf((float)(deg + 1));  // in-degree + self loop
    } else if (node == NN) {
      rowptr[NN] = e0 + excl;  // == NE (last chunk)
    }
  }
  __syncthreads();
  for (int i = tid; i < nv; i += 256) {
    int2 r = erec[e0 + i];
    int pos = atomicAdd(&lrun[r.y & (CH - 1)], 1);
    esrc[e0 + pos] = r.x;
  }
}

// ---------------- MFMA GEMM1: xw1'[n] = dinv[n]*(x[n] @ W1), fp8 out ----------------
// fp8 row layout: ushort at pos t holds features (t, t+64); in C-layout these are
// cols nc*16+m and (nc+4)*16+m -- SAME lane, so packing is lane-local.

__global__ __launch_bounds__(256) void k_gemm_mfma(const float* __restrict__ A,
                                                   const unsigned short* __restrict__ Bp,
                                                   const float* __restrict__ dinv,
                                                   unsigned short* __restrict__ C) {
  constexpr int K = 128;
  constexpr int NCH = KF / 16;
  const int wv = blockIdx.x * 4 + (threadIdx.x >> 6);
  const int row0 = wv * 16;
  if (row0 >= NN) return;  // 100000 % 16 == 0
  const int lane = threadIdx.x & 63;
  const int m = lane & 15;
  const int q = lane >> 4;

  floatx4 acc[NCH];
#pragma unroll
  for (int i = 0; i < NCH; ++i) acc[i] = (floatx4){0.f, 0.f, 0.f, 0.f};

  const int arow = row0 + m;
#pragma unroll
  for (int kc = 0; kc < 4; ++kc) {
    const float* ap = A + (size_t)arow * K + kc * 32 + q * 8;
    float4 f0 = *(const float4*)ap;
    float4 f1 = *(const float4*)(ap + 4);
    short8 af;
    af[0] = (short)f2bf(f0.x); af[1] = (short)f2bf(f0.y);
    af[2] = (short)f2bf(f0.z); af[3] = (short)f2bf(f0.w);
    af[4] = (short)f2bf(f1.x); af[5] = (short)f2bf(f1.y);
    af[6] = (short)f2bf(f1.z); af[7] = (short)f2bf(f1.w);
    const unsigned short* bp = Bp + (size_t)kc * NCH * 512;
#pragma unroll
    for (int nc = 0; nc < NCH; ++nc) {
      short8 bfr = *(const short8*)(bp + (size_t)nc * 512 + lane * 8);
      acc[nc] = __builtin_amdgcn_mfma_f32_16x16x32_bf16(af, bfr, acc[nc], 0, 0, 0);
    }
  }

  float ds[4];
#pragma unroll
  for (int r = 0; r < 4; ++r) ds[r] = dinv[row0 + q * 4 + r];
#pragma unroll
  for (int nc = 0; nc < 4; ++nc) {
#pragma unroll
    for (int r = 0; r < 4; ++r) {
      int row = row0 + q * 4 + r;
      C[(size_t)row * 64 + nc * 16 + m] =
          pk_fp8(acc[nc][r] * ds[r], acc[nc + 4][r] * ds[r]);
    }
  }
}

// ---------------- aggregation: paired-edge dword gathers (round-1 form, best measured) ----------------
// Row = 128 B = 32 dwords. Lanes 0-31 process even-offset edges, lanes 32-63
// odd-offset edges; each lane loads one dword = fp8 pairs for features
// (2u, 2u+64) and (2u+1, 2u+65). Halves fold via __shfl_down(.,32).
// agg1: h1'[n] = dinv[n]*relu( dinv[n]*(sum + self) + b1 ), fp8 out
// agg2: out[n] = dinv[n]*(sum + self), bf16 out (uint: low=feat t, high=feat t+64)

template <bool FIRST>
__global__ __launch_bounds__(128) void k_agg(const unsigned short* __restrict__ p,
                                             const float* __restrict__ bias,
                                             const int* __restrict__ rowptr,
                                             const int* __restrict__ esrc,
                                             const float* __restrict__ dinv,
                                             void* __restrict__ outp) {
  const int n = blockIdx.x * 2 + (threadIdx.x >> 6);
  const int t = threadIdx.x & 63;
  const int u = t & 31;      // dword index within the 32-dword row
  const int half = t >> 5;   // which edge of the pair this lane serves
  const unsigned* __restrict__ prow = (const unsigned*)p;

  // accumulators for features 2u, 2u+64, 2u+1, 2u+65
  float a0 = 0.f, a1 = 0.f, a2 = 0.f, a3 = 0.f;

  if (half == 0) {  // self term (prescaled input), added once
    unsigned v = prow[((unsigned)n << 5) + u];
    floatx2 lo = unpk_fp8((unsigned short)(v & 0xffffu));
    floatx2 hi = unpk_fp8((unsigned short)(v >> 16));
    a0 = lo.x; a1 = lo.y; a2 = hi.x; a3 = hi.y;
  }

  const int r0 = rowptr[n];
  const int r1 = rowptr[n + 1];
  int i = r0;

#define PAIR_TIER(NP)                                                  \
  for (; i + 2 * (NP) <= r1; i += 2 * (NP)) {                          \
    const int ib = i + half;                                           \
    unsigned s[NP];                                                    \
    _Pragma("unroll") for (int j = 0; j < (NP); ++j)                   \
        s[j] = (unsigned)esrc[ib + 2 * j];                             \
    unsigned v[NP];                                                    \
    _Pragma("unroll") for (int j = 0; j < (NP); ++j)                   \
        v[j] = prow[(s[j] << 5) + u];                                  \
    _Pragma("unroll") for (int j = 0; j < (NP); ++j) {                 \
      floatx2 lo = unpk_fp8((unsigned short)(v[j] & 0xffffu));         \
      floatx2 hi = unpk_fp8((unsigned short)(v[j] >> 16));             \
      a0 += lo.x; a1 += lo.y; a2 += hi.x; a3 += hi.y;                  \
    }                                                                  \
  }

  PAIR_TIER(8)   // 16 edges / iter
  PAIR_TIER(4)   // 8
  PAIR_TIER(2)   // 4
  PAIR_TIER(1)   // 2
#undef PAIR_TIER

  if (i < r1 && half == 0) {  // odd leftover edge: half 0 only
    unsigned s = (unsigned)esrc[i];
    unsigned v = prow[(s << 5) + u];
    floatx2 lo = unpk_fp8((unsigned short)(v & 0xffffu));
    floatx2 hi = unpk_fp8((unsigned short)(v >> 16));
    a0 += lo.x; a1 += lo.y; a2 += hi.x; a3 += hi.y;
  }

  // fold half-wave partials: lane u gets lane u+32's sums
  a0 += __shfl_down(a0, 32, 64);
  a1 += __shfl_down(a1, 32, 64);
  a2 += __shfl_down(a2, 32, 64);
  a3 += __shfl_down(a3, 32, 64);

  if (half == 0) {
    const float dn = dinv[n];
    if (FIRST) {
      float2 blo = *(const float2*)(bias + 2 * u);       // bias[2u], bias[2u+1]
      float2 bhi = *(const float2*)(bias + 64 + 2 * u);  // bias[2u+64], bias[2u+65]
      float x0 = fmaxf(fmaf(dn, a0, blo.x), 0.f) * dn;   // feat 2u
      float x1 = fmaxf(fmaf(dn, a1, bhi.x), 0.f) * dn;   // feat 2u+64
      float x2 = fmaxf(fmaf(dn, a2, blo.y), 0.f) * dn;   // feat 2u+1
      float x3 = fmaxf(fmaf(dn, a3, bhi.y), 0.f) * dn;   // feat 2u+65
      unsigned lo = pk_fp8(x0, x1);
      unsigned hi = pk_fp8(x2, x3);
      ((unsigned*)outp)[((unsigned)n << 5) + u] = lo | (hi << 16);
    } else {
      float x0 = a0 * dn, x1 = a1 * dn, x2 = a2 * dn, x3 = a3 * dn;
      uintx2 w;
      w.x = (unsigned)f2bf(x0) | ((unsigned)f2bf(x1) << 16);
      w.y = (unsigned)f2bf(x2) | ((unsigned)f2bf(x3) << 16);
      ((uintx2*)outp)[((unsigned)n << 5) + u] = w;
    }
  }
}

// ---------------- fused mean-pool + mini-GEMM + heads (one block per graph) ----------------
// agg2 bf16 rows: uint at pos t = features (t, t+64)

__global__ __launch_bounds__(256) void k_poolheads(const unsigned* __restrict__ hp,
                                                   const int* __restrict__ batch,
                                                   const float* __restrict__ W2,
                                                   const float* __restrict__ b2,
                                                   const float* __restrict__ Wg,
                                                   const float* __restrict__ bg,
                                                   const float* __restrict__ Wf,
                                                   const float* __restrict__ bfb,
                                                   float* __restrict__ out) {
  __shared__ float sh[4][128];
  __shared__ float pr[KF];
  __shared__ float p[H2F];
  __shared__ int bnd[2];
  const int g = blockIdx.x;
  const int tid = threadIdx.x;
  if (tid < 2) {
    int target = g + tid;
    int lo = 0, hi = NN;
    while (lo < hi) { int mid = (lo + hi) >> 1; if (batch[mid] < target) lo = mid + 1; else hi = mid; }
    bnd[tid] = lo;
  }
  __syncthreads();
  const int start = bnd[0], end = bnd[1];
  const int t = tid & 63, wv = tid >> 6;

  float sx = 0.f, sy = 0.f;
  int n = start + wv;
  for (; n + 12 < end; n += 16) {
    unsigned u0 = hp[(size_t)n * 64 + t];
    unsigned u1 = hp[(size_t)(n + 4) * 64 + t];
    unsigned u2 = hp[(size_t)(n + 8) * 64 + t];
    unsigned u3 = hp[(size_t)(n + 12) * 64 + t];
    float2 f0 = bf2f(u0), f1 = bf2f(u1), f2 = bf2f(u2), f3 = bf2f(u3);
    sx += (f0.x + f1.x) + (f2.x + f3.x);
    sy += (f0.y + f1.y) + (f2.y + f3.y);
  }
  for (; n < end; n += 4) {
    float2 f = bf2f(hp[(size_t)n * 64 + t]);
    sx += f.x; sy += f.y;
  }
  sh[wv][2 * t] = sx;
  sh[wv][2 * t + 1] = sy;
  __syncthreads();
  if (wv == 0) {
    float vx = sh[0][2 * t] + sh[1][2 * t] + sh[2][2 * t] + sh[3][2 * t];
    float vy = sh[0][2 * t + 1] + sh[1][2 * t + 1] + sh[2][2 * t + 1] + sh[3][2 * t + 1];
    float c = fmaxf((float)(end - start), 1.f);
    pr[t] = vx / c;        // feature t
    pr[t + 64] = vy / c;   // feature t+64
  }
  __syncthreads();
  float acc = b2[tid];
#pragma unroll 8
  for (int d = 0; d < KF; ++d) acc = fmaf(pr[d], W2[d * H2F + tid], acc);
  p[tid] = acc;
  __syncthreads();
  if (tid < NGRP) {
    float a = bg[tid];
    for (int d = 0; d < H2F; ++d) a = fmaf(p[d], Wg[d * NGRP + tid], a);
    out[g * NGRP + tid] = a;
  } else if (tid >= 64 && tid < 64 + NGRP * NFAM) {
    int u = tid - 64;
    int gg = u / NFAM;
    int ff = u % NFAM;
    float a = bfb[gg * NFAM + ff];
    for (int d = 0; d < H2F; ++d) a = fmaf(p[d], Wf[(gg * H2F + d) * NFAM + ff], a);
    out[NGR * NGRP + (size_t)gg * NGR * NFAM + g * NFAM + ff] = a;
  }
}

// ---------------- launch ----------------

extern "C" void kernel_launch(void* const* d_in, const int* in_sizes, int n_in,
                              void* d_out, int out_size, void* d_ws, size_t ws_size,
                              hipStream_t stream) {
  const float* x    = (const float*)d_in[0];
  const int*   ei   = (const int*)d_in[1];
  const int*   batch= (const int*)d_in[2];
  const float* W1   = (const float*)d_in[3];
  const float* b1   = (const float*)d_in[4];
  const float* W2   = (const float*)d_in[5];
  const float* b2   = (const float*)d_in[6];
  const float* Wg   = (const float*)d_in[7];
  const float* bg   = (const float*)d_in[8];
  const float* Wf   = (const float*)d_in[9];
  const float* bfb  = (const float*)d_in[10];
  float* out = (float*)d_out;

  char* w = (char*)d_ws;
  auto take = [&](size_t bytes) {
    char* p = w;
    w += (bytes + 255) & ~(size_t)255;
    return (void*)p;
  };
  int*   tot   = (int*)take((size_t)NCHUNK * 4);
  int*   cbase = (int*)take((size_t)(NCHUNK + 1) * 4);
  int*   cursor= (int*)take((size_t)NCHUNK * 4);
  int2*  erec  = (int2*)take((size_t)NE * 8);
  int*   esrc  = (int*)take((size_t)NE * 4);
  int*   rowptr= (int*)take((size_t)(NN + 1) * 4);
  float* dinv  = (float*)take((size_t)NN * 4);
  unsigned short* Bp1 = (unsigned short*)take((size_t)KF * KF * 2);
  unsigned short* xw1 = (unsigned short*)take((size_t)NN * 64 * 2);  // fp8 pairs
  unsigned short* h1  = (unsigned short*)take((size_t)NN * 64 * 2);  // fp8 pairs
  unsigned* agg2= (unsigned*)take((size_t)NN * KF * 2);

  hipMemsetAsync(tot, 0, (size_t)NCHUNK * 4, stream);
  k_histprep<<<NT + PREPB_BLKS, 256, 0, stream>>>(ei, tot, W1, Bp1);
  k_scantot<<<1, 256, 0, stream>>>(tot, cbase, cursor);
  k_pscatter<<<NT, 256, 0, stream>>>(ei, cursor, erec);
  k_sort<<<NCHUNK, 256, 0, stream>>>(erec, cbase, esrc, rowptr, dinv);

  k_gemm_mfma<<<1563, 256, 0, stream>>>(x, Bp1, dinv, xw1);

  k_agg<true><<<NN / 2, 128, 0, stream>>>(xw1, b1, rowptr, esrc, dinv, h1);
  k_agg<false><<<NN / 2, 128, 0, stream>>>(h1, nullptr, rowptr, esrc, dinv, agg2);

  k_poolheads<<<NGR, 256, 0, stream>>>(agg2, batch, W2, b2, Wg, bg, Wf, bfb, out);
}

// Round 8
// 301.084 us; speedup vs baseline: 1.4607x; 1.0267x over previous
//
#include <hip/hip_runtime.h>

#define NN 100000     // nodes
#define NE 1600000    // edges
#define NGR 512       // graphs
#define KF 128        // IN_F == H1
#define H2F 256
#define NGRP 16
#define NFAM 10

#define CH 128                          // nodes per chunk
#define NCHUNK ((NN + CH - 1) / CH)     // 782
#define PT 6656                         // edges per partition tile (round-1 best)
#define NT ((NE + PT - 1) / PT)         // 241
#define PREPB_BLKS 64                   // 128*128/256

typedef __attribute__((ext_vector_type(8))) short short8;
typedef __attribute__((ext_vector_type(4))) float floatx4;
typedef __attribute__((ext_vector_type(2))) float floatx2;
typedef __attribute__((ext_vector_type(2))) unsigned uintx2;

__device__ __forceinline__ unsigned short f2bf(float f) {
  unsigned u = __float_as_uint(f);
  unsigned r = (u + 0x7fff + ((u >> 16) & 1)) >> 16;
  return (unsigned short)r;
}
__device__ __forceinline__ float2 bf2f(unsigned u) {
  float2 r;
  r.x = __uint_as_float(u << 16);
  r.y = __uint_as_float(u & 0xffff0000u);
  return r;
}
// fp8 e4m3 pair (features t, t+64) <-> floats via gfx950 HW converters
__device__ __forceinline__ unsigned short pk_fp8(float a, float b) {
  return (unsigned short)__builtin_amdgcn_cvt_pk_fp8_f32(a, b, 0, false);
}
__device__ __forceinline__ floatx2 unpk_fp8(unsigned short u) {
  return __builtin_amdgcn_cvt_pk_f32_fp8((int)u, false);
}

// ---------------- merged: per-tile chunk histogram -> global tot  |  W1 swizzle ----------------

__global__ __launch_bounds__(256) void k_histprep(const int* __restrict__ ei,
                                                  int* __restrict__ tot,
                                                  const float* __restrict__ W,
                                                  unsigned short* __restrict__ Bp) {
  __shared__ int lh[NCHUNK];
  int tid = threadIdx.x;
  if (blockIdx.x >= NT) {
    int idx = (blockIdx.x - NT) * 256 + tid;
    int j = idx & 7;
    int l = (idx >> 3) & 63;
    int rest = idx >> 9;
    int nc = rest & 7;
    int kc = rest >> 3;
    int k = kc * 32 + (l >> 4) * 8 + j;
    int nn = nc * 16 + (l & 15);
    Bp[idx] = f2bf(W[k * KF + nn]);
    return;
  }
  for (int g = tid; g < NCHUNK; g += 256) lh[g] = 0;
  __syncthreads();
  int base = blockIdx.x * PT;
  int nv = min(PT, NE - base);
  for (int i = tid; i < nv; i += 256) atomicAdd(&lh[ei[NE + base + i] >> 7], 1);
  __syncthreads();
  for (int g = tid; g < NCHUNK; g += 256) {
    int v = lh[g];
    if (v) atomicAdd(&tot[g], v);
  }
}

// ---------------- exclusive scan tot -> cbase; init cursor ----------------

__global__ __launch_bounds__(256) void k_scantot(const int* __restrict__ tot,
                                                 int* __restrict__ cbase,
                                                 int* __restrict__ cursor) {
  __shared__ int ssc[256];
  int tid = threadIdx.x;
  int v4[4]; int loc = 0;
#pragma unroll
  for (int j = 0; j < 4; ++j) {
    int idx = tid * 4 + j;
    v4[j] = (idx < NCHUNK) ? tot[idx] : 0;
    loc += v4[j];
  }
  ssc[tid] = loc;
  __syncthreads();
  for (int off = 1; off < 256; off <<= 1) {
    int val = (tid >= off) ? ssc[tid - off] : 0;
    __syncthreads();
    ssc[tid] += val;
    __syncthreads();
  }
  int excl = ssc[tid] - loc;
#pragma unroll
  for (int j = 0; j < 4; ++j) {
    int idx = tid * 4 + j;
    if (idx < NCHUNK) { cbase[idx] = excl; cursor[idx] = excl; }
    excl += v4[j];
  }
  if (tid == 255) cbase[NCHUNK] = excl;  // == NE
}

// ---------------- partition: LDS-staged, cursor-reserved per-chunk slices ----------------

__global__ __launch_bounds__(256) void k_pscatter(const int* __restrict__ ei,
                                                  int* __restrict__ cursor,
                                                  int2* __restrict__ erec) {
  __shared__ int2 stage[PT];
  __shared__ int lstart[NCHUNK];
  __shared__ int lrun[NCHUNK];
  __shared__ int gbase[NCHUNK];
  __shared__ int ssc[256];
  int t0 = blockIdx.x, tid = threadIdx.x;
  for (int g = tid; g < NCHUNK; g += 256) lrun[g] = 0;
  __syncthreads();
  int base = t0 * PT;
  int nv = min(PT, NE - base);
  for (int i = tid; i < nv; i += 256) atomicAdd(&lrun[ei[NE + base + i] >> 7], 1);
  __syncthreads();
  int v4[4]; int loc = 0;
#pragma unroll
  for (int j = 0; j < 4; ++j) {
    int idx = tid * 4 + j;
    v4[j] = (idx < NCHUNK) ? lrun[idx] : 0;
    loc += v4[j];
  }
  ssc[tid] = loc;
  __syncthreads();
  for (int off = 1; off < 256; off <<= 1) {
    int val = (tid >= off) ? ssc[tid - off] : 0;
    __syncthreads();
    ssc[tid] += val;
    __syncthreads();
  }
  int excl = ssc[tid] - loc;
#pragma unroll
  for (int j = 0; j < 4; ++j) {
    int idx = tid * 4 + j;
    if (idx < NCHUNK) lstart[idx] = excl;
    excl += v4[j];
  }
  __syncthreads();
  for (int g = tid; g < NCHUNK; g += 256) {
    int cnt = ((g + 1 < NCHUNK) ? lstart[g + 1] : nv) - lstart[g];
    gbase[g] = cnt ? atomicAdd(&cursor[g], cnt) : 0;
    lrun[g] = lstart[g];
  }
  __syncthreads();
  for (int i = tid; i < nv; i += 256) {
    int s = ei[base + i], d = ei[NE + base + i];
    int pos = atomicAdd(&lrun[d >> 7], 1);
    stage[pos] = make_int2(s, d);
  }
  __syncthreads();
  for (int j = tid; j < nv; j += 256) {
    int2 r = stage[j];
    int g = r.y >> 7;
    erec[gbase[g] + (j - lstart[g])] = r;
  }
}

// ---------------- per-chunk counting sort into packed per-node runs (+dinv, +ew) ----------------
// ew[e] = dinv[dst_e]  (per-edge weight for the fused per-graph conv2+pool kernel)

__global__ __launch_bounds__(256) void k_sort(const int2* __restrict__ erec,
                                              const int* __restrict__ cbase,
                                              int* __restrict__ esrc,
                                              float* __restrict__ ew,
                                              int* __restrict__ rowptr,
                                              float* __restrict__ dinv) {
  __shared__ int hist[CH];
  __shared__ int lrun[CH];
  __shared__ float ldv[CH];
  __shared__ int sc[256];
  const int c = blockIdx.x, tid = threadIdx.x;
  const int e0 = cbase[c], e1 = cbase[c + 1];
  const int nv = e1 - e0;
  if (tid < CH) hist[tid] = 0;
  __syncthreads();
  for (int i = tid; i < nv; i += 256) atomicAdd(&hist[erec[e0 + i].y & (CH - 1)], 1);
  __syncthreads();
  int deg = (tid < CH) ? hist[tid] : 0;
  sc[tid] = deg;
  __syncthreads();
  for (int off = 1; off < 256; off <<= 1) {
    int val = (tid >= off) ? sc[tid - off] : 0;
    __syncthreads();
    sc[tid] += val;
    __syncthreads();
  }
  int excl = sc[tid] - deg;
  int node = c * CH + tid;
  if (tid < CH) {
    lrun[tid] = excl;
    if (node < NN) {
      float dv = rsqrtf((float)(deg + 1));  // in-degree + self loop
      rowptr[node] = e0 + excl;
      dinv[node] = dv;
      ldv[tid] = dv;
    } else if (node == NN) {
      rowptr[NN] = e0 + excl;  // == NE (last chunk)
    }
  }
  __syncthreads();
  for (int i = tid; i < nv; i += 256) {
    int2 r = erec[e0 + i];
    int ln = r.y & (CH - 1);
    int pos = atomicAdd(&lrun[ln], 1);
    esrc[e0 + pos] = r.x;
    ew[e0 + pos] = ldv[ln];
  }
}

// ---------------- MFMA GEMM1: xw1'[n] = dinv[n]*(x[n] @ W1), fp8 out ----------------
// fp8 row layout: ushort at pos t holds features (t, t+64); in C-layout these are
// cols nc*16+m and (nc+4)*16+m -- SAME lane, so packing is lane-local.

__global__ __launch_bounds__(256) void k_gemm_mfma(const float* __restrict__ A,
                                                   const unsigned short* __restrict__ Bp,
                                                   const float* __restrict__ dinv,
                                                   unsigned short* __restrict__ C) {
  constexpr int K = 128;
  constexpr int NCH = KF / 16;
  const int wv = blockIdx.x * 4 + (threadIdx.x >> 6);
  const int row0 = wv * 16;
  if (row0 >= NN) return;  // 100000 % 16 == 0
  const int lane = threadIdx.x & 63;
  const int m = lane & 15;
  const int q = lane >> 4;

  floatx4 acc[NCH];
#pragma unroll
  for (int i = 0; i < NCH; ++i) acc[i] = (floatx4){0.f, 0.f, 0.f, 0.f};

  const int arow = row0 + m;
#pragma unroll
  for (int kc = 0; kc < 4; ++kc) {
    const float* ap = A + (size_t)arow * K + kc * 32 + q * 8;
    float4 f0 = *(const float4*)ap;
    float4 f1 = *(const float4*)(ap + 4);
    short8 af;
    af[0] = (short)f2bf(f0.x); af[1] = (short)f2bf(f0.y);
    af[2] = (short)f2bf(f0.z); af[3] = (short)f2bf(f0.w);
    af[4] = (short)f2bf(f1.x); af[5] = (short)f2bf(f1.y);
    af[6] = (short)f2bf(f1.z); af[7] = (short)f2bf(f1.w);
    const unsigned short* bp = Bp + (size_t)kc * NCH * 512;
#pragma unroll
    for (int nc = 0; nc < NCH; ++nc) {
      short8 bfr = *(const short8*)(bp + (size_t)nc * 512 + lane * 8);
      acc[nc] = __builtin_amdgcn_mfma_f32_16x16x32_bf16(af, bfr, acc[nc], 0, 0, 0);
    }
  }

  float ds[4];
#pragma unroll
  for (int r = 0; r < 4; ++r) ds[r] = dinv[row0 + q * 4 + r];
#pragma unroll
  for (int nc = 0; nc < 4; ++nc) {
#pragma unroll
    for (int r = 0; r < 4; ++r) {
      int row = row0 + q * 4 + r;
      C[(size_t)row * 64 + nc * 16 + m] =
          pk_fp8(acc[nc][r] * ds[r], acc[nc + 4][r] * ds[r]);
    }
  }
}

// ---------------- aggregation pass 1: paired-edge dword gathers (round-1 form) ----------------
// Row = 128 B = 32 dwords. Lanes 0-31 process even-offset edges, lanes 32-63
// odd-offset edges; each lane loads one dword = fp8 pairs for features
// (2u, 2u+64) and (2u+1, 2u+65). Halves fold via __shfl_down(.,32).
// h1'[n] = dinv[n]*relu( dinv[n]*(sum + self) + b1 ), fp8 out

__global__ __launch_bounds__(128) void k_agg1(const unsigned short* __restrict__ p,
                                              const float* __restrict__ bias,
                                              const int* __restrict__ rowptr,
                                              const int* __restrict__ esrc,
                                              const float* __restrict__ dinv,
                                              unsigned short* __restrict__ outp) {
  const int n = blockIdx.x * 2 + (threadIdx.x >> 6);
  const int t = threadIdx.x & 63;
  const int u = t & 31;      // dword index within the 32-dword row
  const int half = t >> 5;   // which edge of the pair this lane serves
  const unsigned* __restrict__ prow = (const unsigned*)p;

  // accumulators for features 2u, 2u+64, 2u+1, 2u+65
  float a0 = 0.f, a1 = 0.f, a2 = 0.f, a3 = 0.f;

  if (half == 0) {  // self term (prescaled input), added once
    unsigned v = prow[((unsigned)n << 5) + u];
    floatx2 lo = unpk_fp8((unsigned short)(v & 0xffffu));
    floatx2 hi = unpk_fp8((unsigned short)(v >> 16));
    a0 = lo.x; a1 = lo.y; a2 = hi.x; a3 = hi.y;
  }

  const int r0 = rowptr[n];
  const int r1 = rowptr[n + 1];
  int i = r0;

#define PAIR_TIER(NP)                                                  \
  for (; i + 2 * (NP) <= r1; i += 2 * (NP)) {                          \
    const int ib = i + half;                                           \
    unsigned s[NP];                                                    \
    _Pragma("unroll") for (int j = 0; j < (NP); ++j)                   \
        s[j] = (unsigned)esrc[ib + 2 * j];                             \
    unsigned v[NP];                                                    \
    _Pragma("unroll") for (int j = 0; j < (NP); ++j)                   \
        v[j] = prow[(s[j] << 5) + u];                                  \
    _Pragma("unroll") for (int j = 0; j < (NP); ++j) {                 \
      floatx2 lo = unpk_fp8((unsigned short)(v[j] & 0xffffu));         \
      floatx2 hi = unpk_fp8((unsigned short)(v[j] >> 16));             \
      a0 += lo.x; a1 += lo.y; a2 += hi.x; a3 += hi.y;                  \
    }                                                                  \
  }

  PAIR_TIER(8)   // 16 edges / iter
  PAIR_TIER(4)   // 8
  PAIR_TIER(2)   // 4
  PAIR_TIER(1)   // 2
#undef PAIR_TIER

  if (i < r1 && half == 0) {  // odd leftover edge: half 0 only
    unsigned s = (unsigned)esrc[i];
    unsigned v = prow[(s << 5) + u];
    floatx2 lo = unpk_fp8((unsigned short)(v & 0xffffu));
    floatx2 hi = unpk_fp8((unsigned short)(v >> 16));
    a0 += lo.x; a1 += lo.y; a2 += hi.x; a3 += hi.y;
  }

  // fold half-wave partials: lane u gets lane u+32's sums
  a0 += __shfl_down(a0, 32, 64);
  a1 += __shfl_down(a1, 32, 64);
  a2 += __shfl_down(a2, 32, 64);
  a3 += __shfl_down(a3, 32, 64);

  if (half == 0) {
    const float dn = dinv[n];
    float2 blo = *(const float2*)(bias + 2 * u);       // bias[2u], bias[2u+1]
    float2 bhi = *(const float2*)(bias + 64 + 2 * u);  // bias[2u+64], bias[2u+65]
    float x0 = fmaxf(fmaf(dn, a0, blo.x), 0.f) * dn;   // feat 2u
    float x1 = fmaxf(fmaf(dn, a1, bhi.x), 0.f) * dn;   // feat 2u+64
    float x2 = fmaxf(fmaf(dn, a2, blo.y), 0.f) * dn;   // feat 2u+1
    float x3 = fmaxf(fmaf(dn, a3, bhi.y), 0.f) * dn;   // feat 2u+65
    unsigned lo = pk_fp8(x0, x1);
    unsigned hi = pk_fp8(x2, x3);
    ((unsigned*)outp)[((unsigned)n << 5) + u] = lo | (hi << 16);
  }
}

// ---------------- fused conv2 + mean-pool + mini-GEMM + heads (one block per graph) ------------
// batch is sorted -> graph g's nodes are contiguous [start,end) and (CSR-by-dst)
// its edges are the contiguous range [rowptr[start], rowptr[end]).
// pooled[g] = (1/cnt) * ( sum_edges ew[e]*h1'[esrc[e]] + sum_{n in g} dinv[n]*h1'[n] )
// 8 waves stream the flat edge range (2 edges/wave/step, stride 16, 4x unrolled).

__global__ __launch_bounds__(512) void k_aggpool(const unsigned short* __restrict__ p,
                                                 const int* __restrict__ batch,
                                                 const int* __restrict__ rowptr,
                                                 const int* __restrict__ esrc,
                                                 const float* __restrict__ ew,
                                                 const float* __restrict__ dinv,
                                                 const float* __restrict__ W2,
                                                 const float* __restrict__ b2,
                                                 const float* __restrict__ Wg,
                                                 const float* __restrict__ bg,
                                                 const float* __restrict__ Wf,
                                                 const float* __restrict__ bfb,
                                                 float* __restrict__ out) {
  __shared__ float sacc[8][128];
  __shared__ float pr[KF];
  __shared__ float pp[H2F];
  __shared__ int bnd[2];
  const int g = blockIdx.x;
  const int tid = threadIdx.x;
  if (tid < 2) {
    int target = g + tid;
    int lo = 0, hi = NN;
    while (lo < hi) { int mid = (lo + hi) >> 1; if (batch[mid] < target) lo = mid + 1; else hi = mid; }
    bnd[tid] = lo;
  }
  __syncthreads();
  const int start = bnd[0], end = bnd[1];
  const int wv = tid >> 6, t = tid & 63, u = t & 31, half = t >> 5;
  const unsigned* __restrict__ prow = (const unsigned*)p;

  // accumulators for features 2u, 2u+64, 2u+1, 2u+65
  float a0 = 0.f, a1 = 0.f, a2 = 0.f, a3 = 0.f;

  const int e0 = rowptr[start];
  const int e1 = rowptr[end];  // end may be NN; rowptr[NN] == NE

#define EDGE_STEP(idx)                                                 \
  {                                                                    \
    unsigned s_ = (unsigned)esrc[(idx)];                               \
    float w_ = ew[(idx)];                                              \
    unsigned v_ = prow[(s_ << 5) + u];                                 \
    floatx2 lo = unpk_fp8((unsigned short)(v_ & 0xffffu));             \
    floatx2 hi = unpk_fp8((unsigned short)(v_ >> 16));                 \
    a0 = fmaf(w_, lo.x, a0); a1 = fmaf(w_, lo.y, a1);                  \
    a2 = fmaf(w_, hi.x, a2); a3 = fmaf(w_, hi.y, a3);                  \
  }

  int i = e0 + wv * 2 + half;
  // 4x unrolled: lane's edges are i, i+16, i+32, i+48 (8 waves x 2 edges = stride 16)
  for (; i + 48 < e1; i += 64) {
    int i0 = i, i1 = i + 16, i2 = i + 32, i3 = i + 48;
    unsigned s0 = (unsigned)esrc[i0], s1 = (unsigned)esrc[i1];
    unsigned s2 = (unsigned)esrc[i2], s3 = (unsigned)esrc[i3];
    float w0 = ew[i0], w1 = ew[i1], w2 = ew[i2], w3 = ew[i3];
    unsigned v0 = prow[(s0 << 5) + u];
    unsigned v1 = prow[(s1 << 5) + u];
    unsigned v2 = prow[(s2 << 5) + u];
    unsigned v3 = prow[(s3 << 5) + u];
    floatx2 f;
    f = unpk_fp8((unsigned short)(v0 & 0xffffu)); a0 = fmaf(w0, f.x, a0); a1 = fmaf(w0, f.y, a1);
    f = unpk_fp8((unsigned short)(v0 >> 16));     a2 = fmaf(w0, f.x, a2); a3 = fmaf(w0, f.y, a3);
    f = unpk_fp8((unsigned short)(v1 & 0xffffu)); a0 = fmaf(w1, f.x, a0); a1 = fmaf(w1, f.y, a1);
    f = unpk_fp8((unsigned short)(v1 >> 16));     a2 = fmaf(w1, f.x, a2); a3 = fmaf(w1, f.y, a3);
    f = unpk_fp8((unsigned short)(v2 & 0xffffu)); a0 = fmaf(w2, f.x, a0); a1 = fmaf(w2, f.y, a1);
    f = unpk_fp8((unsigned short)(v2 >> 16));     a2 = fmaf(w2, f.x, a2); a3 = fmaf(w2, f.y, a3);
    f = unpk_fp8((unsigned short)(v3 & 0xffffu)); a0 = fmaf(w3, f.x, a0); a1 = fmaf(w3, f.y, a1);
    f = unpk_fp8((unsigned short)(v3 >> 16));     a2 = fmaf(w3, f.x, a2); a3 = fmaf(w3, f.y, a3);
  }
  for (; i < e1; i += 16) EDGE_STEP(i)
#undef EDGE_STEP

  // self terms: weight dinv[n]
  for (int n = start + wv * 2 + half; n < end; n += 16) {
    float w_ = dinv[n];
    unsigned v_ = prow[((unsigned)n << 5) + u];
    floatx2 lo = unpk_fp8((unsigned short)(v_ & 0xffffu));
    floatx2 hi = unpk_fp8((unsigned short)(v_ >> 16));
    a0 = fmaf(w_, lo.x, a0); a1 = fmaf(w_, lo.y, a1);
    a2 = fmaf(w_, hi.x, a2); a3 = fmaf(w_, hi.y, a3);
  }

  // fold halves (same features, different edges)
  a0 += __shfl_down(a0, 32, 64);
  a1 += __shfl_down(a1, 32, 64);
  a2 += __shfl_down(a2, 32, 64);
  a3 += __shfl_down(a3, 32, 64);
  if (half == 0) {
    sacc[wv][2 * u] = a0;       // feat 2u
    sacc[wv][2 * u + 1] = a2;   // feat 2u+1
    sacc[wv][2 * u + 64] = a1;  // feat 2u+64
    sacc[wv][2 * u + 65] = a3;  // feat 2u+65
  }
  __syncthreads();
  if (tid < KF) {
    float v = 0.f;
#pragma unroll
    for (int w = 0; w < 8; ++w) v += sacc[w][tid];
    float c = fmaxf((float)(end - start), 1.f);
    pr[tid] = v / c;
  }
  __syncthreads();
  if (tid < H2F) {
    float acc = b2[tid];
#pragma unroll 8
    for (int d = 0; d < KF; ++d) acc = fmaf(pr[d], W2[d * H2F + tid], acc);
    pp[tid] = acc;
  }
  __syncthreads();
  if (tid < NGRP) {
    float a = bg[tid];
    for (int d = 0; d < H2F; ++d) a = fmaf(pp[d], Wg[d * NGRP + tid], a);
    out[g * NGRP + tid] = a;
  } else if (tid >= 64 && tid < 64 + NGRP * NFAM) {
    int uu = tid - 64;
    int gg = uu / NFAM;
    int ff = uu % NFAM;
    float a = bfb[gg * NFAM + ff];
    for (int d = 0; d < H2F; ++d) a = fmaf(pp[d], Wf[(gg * H2F + d) * NFAM + ff], a);
    out[NGR * NGRP + (size_t)gg * NGR * NFAM + g * NFAM + ff] = a;
  }
}

// ---------------- launch ----------------

extern "C" void kernel_launch(void* const* d_in, const int* in_sizes, int n_in,
                              void* d_out, int out_size, void* d_ws, size_t ws_size,
                              hipStream_t stream) {
  const float* x    = (const float*)d_in[0];
  const int*   ei   = (const int*)d_in[1];
  const int*   batch= (const int*)d_in[2];
  const float* W1   = (const float*)d_in[3];
  const float* b1   = (const float*)d_in[4];
  const float* W2   = (const float*)d_in[5];
  const float* b2   = (const float*)d_in[6];
  const float* Wg   = (const float*)d_in[7];
  const float* bg   = (const float*)d_in[8];
  const float* Wf   = (const float*)d_in[9];
  const float* bfb  = (const float*)d_in[10];
  float* out = (float*)d_out;

  char* w = (char*)d_ws;
  auto take = [&](size_t bytes) {
    char* p = w;
    w += (bytes + 255) & ~(size_t)255;
    return (void*)p;
  };
  int*   tot   = (int*)take((size_t)NCHUNK * 4);
  int*   cbase = (int*)take((size_t)(NCHUNK + 1) * 4);
  int*   cursor= (int*)take((size_t)NCHUNK * 4);
  int2*  erec  = (int2*)take((size_t)NE * 8);
  int*   esrc  = (int*)take((size_t)NE * 4);
  float* ew    = (float*)take((size_t)NE * 4);
  int*   rowptr= (int*)take((size_t)(NN + 1) * 4);
  float* dinv  = (float*)take((size_t)NN * 4);
  unsigned short* Bp1 = (unsigned short*)take((size_t)KF * KF * 2);
  unsigned short* xw1 = (unsigned short*)take((size_t)NN * 64 * 2);  // fp8 pairs
  unsigned short* h1  = (unsigned short*)take((size_t)NN * 64 * 2);  // fp8 pairs

  hipMemsetAsync(tot, 0, (size_t)NCHUNK * 4, stream);
  k_histprep<<<NT + PREPB_BLKS, 256, 0, stream>>>(ei, tot, W1, Bp1);
  k_scantot<<<1, 256, 0, stream>>>(tot, cbase, cursor);
  k_pscatter<<<NT, 256, 0, stream>>>(ei, cursor, erec);
  k_sort<<<NCHUNK, 256, 0, stream>>>(erec, cbase, esrc, ew, rowptr, dinv);

  k_gemm_mfma<<<1563, 256, 0, stream>>>(x, Bp1, dinv, xw1);

  k_agg1<<<NN / 2, 128, 0, stream>>>(xw1, b1, rowptr, esrc, dinv, h1);
  k_aggpool<<<NGR, 512, 0, stream>>>(h1, batch, rowptr, esrc, ew, dinv,
                                     W2, b2, Wg, bg, Wf, bfb, out);
}

// Round 9
// 296.973 us; speedup vs baseline: 1.4809x; 1.0138x over previous
//
#include <hip/hip_runtime.h>

#define NN 100000     // nodes
#define NE 1600000    // edges
#define NGR 512       // graphs
#define KF 128        // IN_F == H1
#define H2F 256
#define NGRP 16
#define NFAM 10

#define CH 128                          // nodes per chunk
#define NCHUNK ((NN + CH - 1) / CH)     // 782
#define PT 6656                         // edges per partition tile (round-1 best)
#define NT ((NE + PT - 1) / PT)         // 241
#define PREPB_BLKS 64                   // 128*128/256

#define NSPLIT 8                        // blocks per graph for fused conv2+pool

typedef __attribute__((ext_vector_type(8))) short short8;
typedef __attribute__((ext_vector_type(4))) float floatx4;
typedef __attribute__((ext_vector_type(2))) float floatx2;

__device__ __forceinline__ unsigned short f2bf(float f) {
  unsigned u = __float_as_uint(f);
  unsigned r = (u + 0x7fff + ((u >> 16) & 1)) >> 16;
  return (unsigned short)r;
}
// fp8 e4m3 pair (features t, t+64) <-> floats via gfx950 HW converters
__device__ __forceinline__ unsigned short pk_fp8(float a, float b) {
  return (unsigned short)__builtin_amdgcn_cvt_pk_fp8_f32(a, b, 0, false);
}
__device__ __forceinline__ floatx2 unpk_fp8(unsigned short u) {
  return __builtin_amdgcn_cvt_pk_f32_fp8((int)u, false);
}

// ---------------- merged: per-tile chunk histogram -> global tot  |  W1 swizzle ----------------

__global__ __launch_bounds__(256) void k_histprep(const int* __restrict__ ei,
                                                  int* __restrict__ tot,
                                                  const float* __restrict__ W,
                                                  unsigned short* __restrict__ Bp) {
  __shared__ int lh[NCHUNK];
  int tid = threadIdx.x;
  if (blockIdx.x >= NT) {
    int idx = (blockIdx.x - NT) * 256 + tid;
    int j = idx & 7;
    int l = (idx >> 3) & 63;
    int rest = idx >> 9;
    int nc = rest & 7;
    int kc = rest >> 3;
    int k = kc * 32 + (l >> 4) * 8 + j;
    int nn = nc * 16 + (l & 15);
    Bp[idx] = f2bf(W[k * KF + nn]);
    return;
  }
  for (int g = tid; g < NCHUNK; g += 256) lh[g] = 0;
  __syncthreads();
  int base = blockIdx.x * PT;
  int nv = min(PT, NE - base);
  for (int i = tid; i < nv; i += 256) atomicAdd(&lh[ei[NE + base + i] >> 7], 1);
  __syncthreads();
  for (int g = tid; g < NCHUNK; g += 256) {
    int v = lh[g];
    if (v) atomicAdd(&tot[g], v);
  }
}

// ---------------- exclusive scan tot -> cbase; init cursor ----------------

__global__ __launch_bounds__(256) void k_scantot(const int* __restrict__ tot,
                                                 int* __restrict__ cbase,
                                                 int* __restrict__ cursor) {
  __shared__ int ssc[256];
  int tid = threadIdx.x;
  int v4[4]; int loc = 0;
#pragma unroll
  for (int j = 0; j < 4; ++j) {
    int idx = tid * 4 + j;
    v4[j] = (idx < NCHUNK) ? tot[idx] : 0;
    loc += v4[j];
  }
  ssc[tid] = loc;
  __syncthreads();
  for (int off = 1; off < 256; off <<= 1) {
    int val = (tid >= off) ? ssc[tid - off] : 0;
    __syncthreads();
    ssc[tid] += val;
    __syncthreads();
  }
  int excl = ssc[tid] - loc;
#pragma unroll
  for (int j = 0; j < 4; ++j) {
    int idx = tid * 4 + j;
    if (idx < NCHUNK) { cbase[idx] = excl; cursor[idx] = excl; }
    excl += v4[j];
  }
  if (tid == 255) cbase[NCHUNK] = excl;  // == NE
}

// ---------------- partition: LDS-staged, cursor-reserved per-chunk slices ----------------

__global__ __launch_bounds__(256) void k_pscatter(const int* __restrict__ ei,
                                                  int* __restrict__ cursor,
                                                  int2* __restrict__ erec) {
  __shared__ int2 stage[PT];
  __shared__ int lstart[NCHUNK];
  __shared__ int lrun[NCHUNK];
  __shared__ int gbase[NCHUNK];
  __shared__ int ssc[256];
  int t0 = blockIdx.x, tid = threadIdx.x;
  for (int g = tid; g < NCHUNK; g += 256) lrun[g] = 0;
  __syncthreads();
  int base = t0 * PT;
  int nv = min(PT, NE - base);
  for (int i = tid; i < nv; i += 256) atomicAdd(&lrun[ei[NE + base + i] >> 7], 1);
  __syncthreads();
  int v4[4]; int loc = 0;
#pragma unroll
  for (int j = 0; j < 4; ++j) {
    int idx = tid * 4 + j;
    v4[j] = (idx < NCHUNK) ? lrun[idx] : 0;
    loc += v4[j];
  }
  ssc[tid] = loc;
  __syncthreads();
  for (int off = 1; off < 256; off <<= 1) {
    int val = (tid >= off) ? ssc[tid - off] : 0;
    __syncthreads();
    ssc[tid] += val;
    __syncthreads();
  }
  int excl = ssc[tid] - loc;
#pragma unroll
  for (int j = 0; j < 4; ++j) {
    int idx = tid * 4 + j;
    if (idx < NCHUNK) lstart[idx] = excl;
    excl += v4[j];
  }
  __syncthreads();
  for (int g = tid; g < NCHUNK; g += 256) {
    int cnt = ((g + 1 < NCHUNK) ? lstart[g + 1] : nv) - lstart[g];
    gbase[g] = cnt ? atomicAdd(&cursor[g], cnt) : 0;
    lrun[g] = lstart[g];
  }
  __syncthreads();
  for (int i = tid; i < nv; i += 256) {
    int s = ei[base + i], d = ei[NE + base + i];
    int pos = atomicAdd(&lrun[d >> 7], 1);
    stage[pos] = make_int2(s, d);
  }
  __syncthreads();
  for (int j = tid; j < nv; j += 256) {
    int2 r = stage[j];
    int g = r.y >> 7;
    erec[gbase[g] + (j - lstart[g])] = r;
  }
}

// ---------------- per-chunk counting sort into packed per-node runs (+dinv, +ew) ----------------
// ew[e] = dinv[dst_e]  (per-edge weight for the fused per-graph conv2+pool kernel)

__global__ __launch_bounds__(256) void k_sort(const int2* __restrict__ erec,
                                              const int* __restrict__ cbase,
                                              int* __restrict__ esrc,
                                              float* __restrict__ ew,
                                              int* __restrict__ rowptr,
                                              float* __restrict__ dinv) {
  __shared__ int hist[CH];
  __shared__ int lrun[CH];
  __shared__ float ldv[CH];
  __shared__ int sc[256];
  const int c = blockIdx.x, tid = threadIdx.x;
  const int e0 = cbase[c], e1 = cbase[c + 1];
  const int nv = e1 - e0;
  if (tid < CH) hist[tid] = 0;
  __syncthreads();
  for (int i = tid; i < nv; i += 256) atomicAdd(&hist[erec[e0 + i].y & (CH - 1)], 1);
  __syncthreads();
  int deg = (tid < CH) ? hist[tid] : 0;
  sc[tid] = deg;
  __syncthreads();
  for (int off = 1; off < 256; off <<= 1) {
    int val = (tid >= off) ? sc[tid - off] : 0;
    __syncthreads();
    sc[tid] += val;
    __syncthreads();
  }
  int excl = sc[tid] - deg;
  int node = c * CH + tid;
  if (tid < CH) {
    lrun[tid] = excl;
    if (node < NN) {
      float dv = rsqrtf((float)(deg + 1));  // in-degree + self loop
      rowptr[node] = e0 + excl;
      dinv[node] = dv;
      ldv[tid] = dv;
    } else if (node == NN) {
      rowptr[NN] = e0 + excl;  // == NE (last chunk)
    }
  }
  __syncthreads();
  for (int i = tid; i < nv; i += 256) {
    int2 r = erec[e0 + i];
    int ln = r.y & (CH - 1);
    int pos = atomicAdd(&lrun[ln], 1);
    esrc[e0 + pos] = r.x;
    ew[e0 + pos] = ldv[ln];
  }
}

// ---------------- MFMA GEMM1: xw1'[n] = dinv[n]*(x[n] @ W1), fp8 out ----------------
// fp8 row layout: ushort at pos t holds features (t, t+64); in C-layout these are
// cols nc*16+m and (nc+4)*16+m -- SAME lane, so packing is lane-local.

__global__ __launch_bounds__(256) void k_gemm_mfma(const float* __restrict__ A,
                                                   const unsigned short* __restrict__ Bp,
                                                   const float* __restrict__ dinv,
                                                   unsigned short* __restrict__ C) {
  constexpr int K = 128;
  constexpr int NCH = KF / 16;
  const int wv = blockIdx.x * 4 + (threadIdx.x >> 6);
  const int row0 = wv * 16;
  if (row0 >= NN) return;  // 100000 % 16 == 0
  const int lane = threadIdx.x & 63;
  const int m = lane & 15;
  const int q = lane >> 4;

  floatx4 acc[NCH];
#pragma unroll
  for (int i = 0; i < NCH; ++i) acc[i] = (floatx4){0.f, 0.f, 0.f, 0.f};

  const int arow = row0 + m;
#pragma unroll
  for (int kc = 0; kc < 4; ++kc) {
    const float* ap = A + (size_t)arow * K + kc * 32 + q * 8;
    float4 f0 = *(const float4*)ap;
    float4 f1 = *(const float4*)(ap + 4);
    short8 af;
    af[0] = (short)f2bf(f0.x); af[1] = (short)f2bf(f0.y);
    af[2] = (short)f2bf(f0.z); af[3] = (short)f2bf(f0.w);
    af[4] = (short)f2bf(f1.x); af[5] = (short)f2bf(f1.y);
    af[6] = (short)f2bf(f1.z); af[7] = (short)f2bf(f1.w);
    const unsigned short* bp = Bp + (size_t)kc * NCH * 512;
#pragma unroll
    for (int nc = 0; nc < NCH; ++nc) {
      short8 bfr = *(const short8*)(bp + (size_t)nc * 512 + lane * 8);
      acc[nc] = __builtin_amdgcn_mfma_f32_16x16x32_bf16(af, bfr, acc[nc], 0, 0, 0);
    }
  }

  float ds[4];
#pragma unroll
  for (int r = 0; r < 4; ++r) ds[r] = dinv[row0 + q * 4 + r];
#pragma unroll
  for (int nc = 0; nc < 4; ++nc) {
#pragma unroll
    for (int r = 0; r < 4; ++r) {
      int row = row0 + q * 4 + r;
      C[(size_t)row * 64 + nc * 16 + m] =
          pk_fp8(acc[nc][r] * ds[r], acc[nc + 4][r] * ds[r]);
    }
  }
}

// ---------------- aggregation pass 1: paired-edge dword gathers (round-1 form) ----------------
// Row = 128 B = 32 dwords. Lanes 0-31 process even-offset edges, lanes 32-63
// odd-offset edges; each lane loads one dword = fp8 pairs for features
// (2u, 2u+64) and (2u+1, 2u+65). Halves fold via __shfl_down(.,32).
// h1'[n] = dinv[n]*relu( dinv[n]*(sum + self) + b1 ), fp8 out

__global__ __launch_bounds__(128) void k_agg1(const unsigned short* __restrict__ p,
                                              const float* __restrict__ bias,
                                              const int* __restrict__ rowptr,
                                              const int* __restrict__ esrc,
                                              const float* __restrict__ dinv,
                                              unsigned short* __restrict__ outp) {
  const int n = blockIdx.x * 2 + (threadIdx.x >> 6);
  const int t = threadIdx.x & 63;
  const int u = t & 31;      // dword index within the 32-dword row
  const int half = t >> 5;   // which edge of the pair this lane serves
  const unsigned* __restrict__ prow = (const unsigned*)p;

  // accumulators for features 2u, 2u+64, 2u+1, 2u+65
  float a0 = 0.f, a1 = 0.f, a2 = 0.f, a3 = 0.f;

  if (half == 0) {  // self term (prescaled input), added once
    unsigned v = prow[((unsigned)n << 5) + u];
    floatx2 lo = unpk_fp8((unsigned short)(v & 0xffffu));
    floatx2 hi = unpk_fp8((unsigned short)(v >> 16));
    a0 = lo.x; a1 = lo.y; a2 = hi.x; a3 = hi.y;
  }

  const int r0 = rowptr[n];
  const int r1 = rowptr[n + 1];
  int i = r0;

#define PAIR_TIER(NP)                                                  \
  for (; i + 2 * (NP) <= r1; i += 2 * (NP)) {                          \
    const int ib = i + half;                                           \
    unsigned s[NP];                                                    \
    _Pragma("unroll") for (int j = 0; j < (NP); ++j)                   \
        s[j] = (unsigned)esrc[ib + 2 * j];                             \
    unsigned v[NP];                                                    \
    _Pragma("unroll") for (int j = 0; j < (NP); ++j)                   \
        v[j] = prow[(s[j] << 5) + u];                                  \
    _Pragma("unroll") for (int j = 0; j < (NP); ++j) {                 \
      floatx2 lo = unpk_fp8((unsigned short)(v[j] & 0xffffu));         \
      floatx2 hi = unpk_fp8((unsigned short)(v[j] >> 16));             \
      a0 += lo.x; a1 += lo.y; a2 += hi.x; a3 += hi.y;                  \
    }                                                                  \
  }

  PAIR_TIER(8)   // 16 edges / iter
  PAIR_TIER(4)   // 8
  PAIR_TIER(2)   // 4
  PAIR_TIER(1)   // 2
#undef PAIR_TIER

  if (i < r1 && half == 0) {  // odd leftover edge: half 0 only
    unsigned s = (unsigned)esrc[i];
    unsigned v = prow[(s << 5) + u];
    floatx2 lo = unpk_fp8((unsigned short)(v & 0xffffu));
    floatx2 hi = unpk_fp8((unsigned short)(v >> 16));
    a0 += lo.x; a1 += lo.y; a2 += hi.x; a3 += hi.y;
  }

  // fold half-wave partials: lane u gets lane u+32's sums
  a0 += __shfl_down(a0, 32, 64);
  a1 += __shfl_down(a1, 32, 64);
  a2 += __shfl_down(a2, 32, 64);
  a3 += __shfl_down(a3, 32, 64);

  if (half == 0) {
    const float dn = dinv[n];
    float2 blo = *(const float2*)(bias + 2 * u);       // bias[2u], bias[2u+1]
    float2 bhi = *(const float2*)(bias + 64 + 2 * u);  // bias[2u+64], bias[2u+65]
    float x0 = fmaxf(fmaf(dn, a0, blo.x), 0.f) * dn;   // feat 2u
    float x1 = fmaxf(fmaf(dn, a1, bhi.x), 0.f) * dn;   // feat 2u+64
    float x2 = fmaxf(fmaf(dn, a2, blo.y), 0.f) * dn;   // feat 2u+1
    float x3 = fmaxf(fmaf(dn, a3, bhi.y), 0.f) * dn;   // feat 2u+65
    unsigned lo = pk_fp8(x0, x1);
    unsigned hi = pk_fp8(x2, x3);
    ((unsigned*)outp)[((unsigned)n << 5) + u] = lo | (hi << 16);
  }
}

// ---------------- fused conv2 + partial mean-pool (NSPLIT blocks per graph) ----------------
// Graph g's nodes are contiguous [start,end); its CSR-by-dst edges are the
// contiguous flat range [rowptr[start], rowptr[end]). Block (g, part) handles a
// 1/NSPLIT slice of both, accumulates a 128-float partial pooled sum, then
// atomicAdds it into pooled[g][.]. Grid = NGR*NSPLIT = 4096 blocks (wave-count
// fix for round-8's 33%-occupancy fusion).
// Wave layout: 4 waves x 2 edges per step (stride 8); lane u reads dword u of
// the row = features (2u, 2u+64, 2u+1, 2u+65).

__global__ __launch_bounds__(256) void k_aggpart(const unsigned short* __restrict__ p,
                                                 const int* __restrict__ batch,
                                                 const int* __restrict__ rowptr,
                                                 const int* __restrict__ esrc,
                                                 const float* __restrict__ ew,
                                                 const float* __restrict__ dinv,
                                                 float* __restrict__ pooled) {
  __shared__ float sacc[4][128];
  __shared__ int bnd[2];
  const int g = blockIdx.x / NSPLIT;
  const int part = blockIdx.x % NSPLIT;
  const int tid = threadIdx.x;
  if (tid < 2) {
    int target = g + tid;
    int lo = 0, hi = NN;
    while (lo < hi) { int mid = (lo + hi) >> 1; if (batch[mid] < target) lo = mid + 1; else hi = mid; }
    bnd[tid] = lo;
  }
  __syncthreads();
  const int start = bnd[0], end = bnd[1];
  const int wv = tid >> 6, t = tid & 63, u = t & 31, half = t >> 5;
  const unsigned* __restrict__ prow = (const unsigned*)p;

  float a0 = 0.f, a1 = 0.f, a2 = 0.f, a3 = 0.f;

  // edge slice
  const int e0 = rowptr[start];
  const int e1 = rowptr[end];  // rowptr[NN] == NE
  const int elen = e1 - e0;
  const int eper = (elen + NSPLIT - 1) / NSPLIT;
  const int is = min(e0 + part * eper, e1);
  const int ie = min(is + eper, e1);

#define EDGE_STEP(idx)                                                 \
  {                                                                    \
    unsigned s_ = (unsigned)esrc[(idx)];                               \
    float w_ = ew[(idx)];                                              \
    unsigned v_ = prow[(s_ << 5) + u];                                 \
    floatx2 lo = unpk_fp8((unsigned short)(v_ & 0xffffu));             \
    floatx2 hi = unpk_fp8((unsigned short)(v_ >> 16));                 \
    a0 = fmaf(w_, lo.x, a0); a1 = fmaf(w_, lo.y, a1);                  \
    a2 = fmaf(w_, hi.x, a2); a3 = fmaf(w_, hi.y, a3);                  \
  }

  int i = is + wv * 2 + half;
  // 4x unrolled: lane's edges are i, i+8, i+16, i+24 (4 waves x 2 edges = stride 8)
  for (; i + 24 < ie; i += 32) {
    int i0 = i, i1 = i + 8, i2 = i + 16, i3 = i + 24;
    unsigned s0 = (unsigned)esrc[i0], s1 = (unsigned)esrc[i1];
    unsigned s2 = (unsigned)esrc[i2], s3 = (unsigned)esrc[i3];
    float w0 = ew[i0], w1 = ew[i1], w2 = ew[i2], w3 = ew[i3];
    unsigned v0 = prow[(s0 << 5) + u];
    unsigned v1 = prow[(s1 << 5) + u];
    unsigned v2 = prow[(s2 << 5) + u];
    unsigned v3 = prow[(s3 << 5) + u];
    floatx2 f;
    f = unpk_fp8((unsigned short)(v0 & 0xffffu)); a0 = fmaf(w0, f.x, a0); a1 = fmaf(w0, f.y, a1);
    f = unpk_fp8((unsigned short)(v0 >> 16));     a2 = fmaf(w0, f.x, a2); a3 = fmaf(w0, f.y, a3);
    f = unpk_fp8((unsigned short)(v1 & 0xffffu)); a0 = fmaf(w1, f.x, a0); a1 = fmaf(w1, f.y, a1);
    f = unpk_fp8((unsigned short)(v1 >> 16));     a2 = fmaf(w1, f.x, a2); a3 = fmaf(w1, f.y, a3);
    f = unpk_fp8((unsigned short)(v2 & 0xffffu)); a0 = fmaf(w2, f.x, a0); a1 = fmaf(w2, f.y, a1);
    f = unpk_fp8((unsigned short)(v2 >> 16));     a2 = fmaf(w2, f.x, a2); a3 = fmaf(w2, f.y, a3);
    f = unpk_fp8((unsigned short)(v3 & 0xffffu)); a0 = fmaf(w3, f.x, a0); a1 = fmaf(w3, f.y, a1);
    f = unpk_fp8((unsigned short)(v3 >> 16));     a2 = fmaf(w3, f.x, a2); a3 = fmaf(w3, f.y, a3);
  }
  for (; i < ie; i += 8) EDGE_STEP(i)
#undef EDGE_STEP

  // self-node slice: weight dinv[n]
  const int nlen = end - start;
  const int nper = (nlen + NSPLIT - 1) / NSPLIT;
  const int ns = min(start + part * nper, end);
  const int ne = min(ns + nper, end);
  for (int n = ns + wv * 2 + half; n < ne; n += 8) {
    float w_ = dinv[n];
    unsigned v_ = prow[((unsigned)n << 5) + u];
    floatx2 lo = unpk_fp8((unsigned short)(v_ & 0xffffu));
    floatx2 hi = unpk_fp8((unsigned short)(v_ >> 16));
    a0 = fmaf(w_, lo.x, a0); a1 = fmaf(w_, lo.y, a1);
    a2 = fmaf(w_, hi.x, a2); a3 = fmaf(w_, hi.y, a3);
  }

  // fold the two half-wave edge streams
  a0 += __shfl_down(a0, 32, 64);
  a1 += __shfl_down(a1, 32, 64);
  a2 += __shfl_down(a2, 32, 64);
  a3 += __shfl_down(a3, 32, 64);
  if (half == 0) {
    sacc[wv][2 * u] = a0;       // feat 2u
    sacc[wv][2 * u + 1] = a2;   // feat 2u+1
    sacc[wv][2 * u + 64] = a1;  // feat 2u+64
    sacc[wv][2 * u + 65] = a3;  // feat 2u+65
  }
  __syncthreads();
  if (tid < KF) {
    float v = sacc[0][tid] + sacc[1][tid] + sacc[2][tid] + sacc[3][tid];
    atomicAdd(&pooled[(size_t)g * KF + tid], v);
  }
}

// ---------------- heads: mean + W2 GEMM + group/family heads (one block per graph) -------------

__global__ __launch_bounds__(256) void k_heads(const float* __restrict__ pooled,
                                               const int* __restrict__ batch,
                                               const float* __restrict__ W2,
                                               const float* __restrict__ b2,
                                               const float* __restrict__ Wg,
                                               const float* __restrict__ bg,
                                               const float* __restrict__ Wf,
                                               const float* __restrict__ bfb,
                                               float* __restrict__ out) {
  __shared__ float pr[KF];
  __shared__ float pp[H2F];
  __shared__ int bnd[2];
  const int g = blockIdx.x;
  const int tid = threadIdx.x;
  if (tid < 2) {
    int target = g + tid;
    int lo = 0, hi = NN;
    while (lo < hi) { int mid = (lo + hi) >> 1; if (batch[mid] < target) lo = mid + 1; else hi = mid; }
    bnd[tid] = lo;
  }
  __syncthreads();
  if (tid < KF) {
    float c = fmaxf((float)(bnd[1] - bnd[0]), 1.f);
    pr[tid] = pooled[(size_t)g * KF + tid] / c;
  }
  __syncthreads();
  float acc = b2[tid];
#pragma unroll 8
  for (int d = 0; d < KF; ++d) acc = fmaf(pr[d], W2[d * H2F + tid], acc);
  pp[tid] = acc;
  __syncthreads();
  if (tid < NGRP) {
    float a = bg[tid];
    for (int d = 0; d < H2F; ++d) a = fmaf(pp[d], Wg[d * NGRP + tid], a);
    out[g * NGRP + tid] = a;
  } else if (tid >= 64 && tid < 64 + NGRP * NFAM) {
    int uu = tid - 64;
    int gg = uu / NFAM;
    int ff = uu % NFAM;
    float a = bfb[gg * NFAM + ff];
    for (int d = 0; d < H2F; ++d) a = fmaf(pp[d], Wf[(gg * H2F + d) * NFAM + ff], a);
    out[NGR * NGRP + (size_t)gg * NGR * NFAM + g * NFAM + ff] = a;
  }
}

// ---------------- launch ----------------

extern "C" void kernel_launch(void* const* d_in, const int* in_sizes, int n_in,
                              void* d_out, int out_size, void* d_ws, size_t ws_size,
                              hipStream_t stream) {
  const float* x    = (const float*)d_in[0];
  const int*   ei   = (const int*)d_in[1];
  const int*   batch= (const int*)d_in[2];
  const float* W1   = (const float*)d_in[3];
  const float* b1   = (const float*)d_in[4];
  const float* W2   = (const float*)d_in[5];
  const float* b2   = (const float*)d_in[6];
  const float* Wg   = (const float*)d_in[7];
  const float* bg   = (const float*)d_in[8];
  const float* Wf   = (const float*)d_in[9];
  const float* bfb  = (const float*)d_in[10];
  float* out = (float*)d_out;

  char* w = (char*)d_ws;
  auto take = [&](size_t bytes) {
    char* p = w;
    w += (bytes + 255) & ~(size_t)255;
    return (void*)p;
  };
  int*   tot   = (int*)take((size_t)NCHUNK * 4);
  float* pooled= (float*)take((size_t)NGR * KF * 4);  // adjacent to tot: one memset covers both
  int*   cbase = (int*)take((size_t)(NCHUNK + 1) * 4);
  int*   cursor= (int*)take((size_t)NCHUNK * 4);
  int2*  erec  = (int2*)take((size_t)NE * 8);
  int*   esrc  = (int*)take((size_t)NE * 4);
  float* ew    = (float*)take((size_t)NE * 4);
  int*   rowptr= (int*)take((size_t)(NN + 1) * 4);
  float* dinv  = (float*)take((size_t)NN * 4);
  unsigned short* Bp1 = (unsigned short*)take((size_t)KF * KF * 2);
  unsigned short* xw1 = (unsigned short*)take((size_t)NN * 64 * 2);  // fp8 pairs
  unsigned short* h1  = (unsigned short*)take((size_t)NN * 64 * 2);  // fp8 pairs

  // zero tot + pooled in one shot (adjacent in workspace)
  size_t zbytes = (size_t)((char*)pooled - (char*)tot) + (size_t)NGR * KF * 4;
  hipMemsetAsync(tot, 0, zbytes, stream);

  k_histprep<<<NT + PREPB_BLKS, 256, 0, stream>>>(ei, tot, W1, Bp1);
  k_scantot<<<1, 256, 0, stream>>>(tot, cbase, cursor);
  k_pscatter<<<NT, 256, 0, stream>>>(ei, cursor, erec);
  k_sort<<<NCHUNK, 256, 0, stream>>>(erec, cbase, esrc, ew, rowptr, dinv);

  k_gemm_mfma<<<1563, 256, 0, stream>>>(x, Bp1, dinv, xw1);

  k_agg1<<<NN / 2, 128, 0, stream>>>(xw1, b1, rowptr, esrc, dinv, h1);
  k_aggpart<<<NGR * NSPLIT, 256, 0, stream>>>(h1, batch, rowptr, esrc, ew, dinv, pooled);
  k_heads<<<NGR, 256, 0, stream>>>(pooled, batch, W2, b2, Wg, bg, Wf, bfb, out);
}

// Round 10
// 292.389 us; speedup vs baseline: 1.5042x; 1.0157x over previous
//
#include <hip/hip_runtime.h>

#define NN 100000     // nodes
#define NE 1600000    // edges
#define NGR 512       // graphs
#define KF 128        // IN_F == H1
#define H2F 256
#define NGRP 16
#define NFAM 10

#define CH 128                          // nodes per chunk
#define NCHUNK ((NN + CH - 1) / CH)     // 782
#define PT 6656                         // edges per partition tile (round-1 best)
#define NT ((NE + PT - 1) / PT)         // 241
#define PREPB_BLKS 64                   // 128*128/256

#define NSPLIT 8                        // blocks per graph for fused conv2+pool

typedef __attribute__((ext_vector_type(8))) short short8;
typedef __attribute__((ext_vector_type(4))) float floatx4;
typedef __attribute__((ext_vector_type(2))) float floatx2;

__device__ __forceinline__ unsigned short f2bf(float f) {
  unsigned u = __float_as_uint(f);
  unsigned r = (u + 0x7fff + ((u >> 16) & 1)) >> 16;
  return (unsigned short)r;
}
// fp8 e4m3 pair (features t, t+64) <-> floats via gfx950 HW converters
__device__ __forceinline__ unsigned short pk_fp8(float a, float b) {
  return (unsigned short)__builtin_amdgcn_cvt_pk_fp8_f32(a, b, 0, false);
}
__device__ __forceinline__ floatx2 unpk_fp8(unsigned short u) {
  return __builtin_amdgcn_cvt_pk_f32_fp8((int)u, false);
}

// ---------------- merged: per-tile chunk histogram -> global tot  |  W1 swizzle ----------------

__global__ __launch_bounds__(256) void k_histprep(const int* __restrict__ ei,
                                                  int* __restrict__ tot,
                                                  const float* __restrict__ W,
                                                  unsigned short* __restrict__ Bp) {
  __shared__ int lh[NCHUNK];
  int tid = threadIdx.x;
  if (blockIdx.x >= NT) {
    int idx = (blockIdx.x - NT) * 256 + tid;
    int j = idx & 7;
    int l = (idx >> 3) & 63;
    int rest = idx >> 9;
    int nc = rest & 7;
    int kc = rest >> 3;
    int k = kc * 32 + (l >> 4) * 8 + j;
    int nn = nc * 16 + (l & 15);
    Bp[idx] = f2bf(W[k * KF + nn]);
    return;
  }
  for (int g = tid; g < NCHUNK; g += 256) lh[g] = 0;
  __syncthreads();
  int base = blockIdx.x * PT;
  int nv = min(PT, NE - base);
  for (int i = tid; i < nv; i += 256) atomicAdd(&lh[ei[NE + base + i] >> 7], 1);
  __syncthreads();
  for (int g = tid; g < NCHUNK; g += 256) {
    int v = lh[g];
    if (v) atomicAdd(&tot[g], v);
  }
}

// ---------------- exclusive scan tot -> cbase; init cursor ----------------

__global__ __launch_bounds__(256) void k_scantot(const int* __restrict__ tot,
                                                 int* __restrict__ cbase,
                                                 int* __restrict__ cursor) {
  __shared__ int ssc[256];
  int tid = threadIdx.x;
  int v4[4]; int loc = 0;
#pragma unroll
  for (int j = 0; j < 4; ++j) {
    int idx = tid * 4 + j;
    v4[j] = (idx < NCHUNK) ? tot[idx] : 0;
    loc += v4[j];
  }
  ssc[tid] = loc;
  __syncthreads();
  for (int off = 1; off < 256; off <<= 1) {
    int val = (tid >= off) ? ssc[tid - off] : 0;
    __syncthreads();
    ssc[tid] += val;
    __syncthreads();
  }
  int excl = ssc[tid] - loc;
#pragma unroll
  for (int j = 0; j < 4; ++j) {
    int idx = tid * 4 + j;
    if (idx < NCHUNK) { cbase[idx] = excl; cursor[idx] = excl; }
    excl += v4[j];
  }
  if (tid == 255) cbase[NCHUNK] = excl;  // == NE
}

// ---------------- partition: LDS-staged, cursor-reserved per-chunk slices ----------------

__global__ __launch_bounds__(256) void k_pscatter(const int* __restrict__ ei,
                                                  int* __restrict__ cursor,
                                                  int2* __restrict__ erec) {
  __shared__ int2 stage[PT];
  __shared__ int lstart[NCHUNK];
  __shared__ int lrun[NCHUNK];
  __shared__ int gbase[NCHUNK];
  __shared__ int ssc[256];
  int t0 = blockIdx.x, tid = threadIdx.x;
  for (int g = tid; g < NCHUNK; g += 256) lrun[g] = 0;
  __syncthreads();
  int base = t0 * PT;
  int nv = min(PT, NE - base);
  for (int i = tid; i < nv; i += 256) atomicAdd(&lrun[ei[NE + base + i] >> 7], 1);
  __syncthreads();
  int v4[4]; int loc = 0;
#pragma unroll
  for (int j = 0; j < 4; ++j) {
    int idx = tid * 4 + j;
    v4[j] = (idx < NCHUNK) ? lrun[idx] : 0;
    loc += v4[j];
  }
  ssc[tid] = loc;
  __syncthreads();
  for (int off = 1; off < 256; off <<= 1) {
    int val = (tid >= off) ? ssc[tid - off] : 0;
    __syncthreads();
    ssc[tid] += val;
    __syncthreads();
  }
  int excl = ssc[tid] - loc;
#pragma unroll
  for (int j = 0; j < 4; ++j) {
    int idx = tid * 4 + j;
    if (idx < NCHUNK) lstart[idx] = excl;
    excl += v4[j];
  }
  __syncthreads();
  for (int g = tid; g < NCHUNK; g += 256) {
    int cnt = ((g + 1 < NCHUNK) ? lstart[g + 1] : nv) - lstart[g];
    gbase[g] = cnt ? atomicAdd(&cursor[g], cnt) : 0;
    lrun[g] = lstart[g];
  }
  __syncthreads();
  for (int i = tid; i < nv; i += 256) {
    int s = ei[base + i], d = ei[NE + base + i];
    int pos = atomicAdd(&lrun[d >> 7], 1);
    stage[pos] = make_int2(s, d);
  }
  __syncthreads();
  for (int j = tid; j < nv; j += 256) {
    int2 r = stage[j];
    int g = r.y >> 7;
    erec[gbase[g] + (j - lstart[g])] = r;
  }
}

// ---------------- per-chunk counting sort into packed per-node runs (+dinv, +ew) ----------------
// ew[e] = dinv[dst_e]  (per-edge weight for the fused per-graph conv2+pool kernel)

__global__ __launch_bounds__(256) void k_sort(const int2* __restrict__ erec,
                                              const int* __restrict__ cbase,
                                              int* __restrict__ esrc,
                                              float* __restrict__ ew,
                                              int* __restrict__ rowptr,
                                              float* __restrict__ dinv) {
  __shared__ int hist[CH];
  __shared__ int lrun[CH];
  __shared__ float ldv[CH];
  __shared__ int sc[256];
  const int c = blockIdx.x, tid = threadIdx.x;
  const int e0 = cbase[c], e1 = cbase[c + 1];
  const int nv = e1 - e0;
  if (tid < CH) hist[tid] = 0;
  __syncthreads();
  for (int i = tid; i < nv; i += 256) atomicAdd(&hist[erec[e0 + i].y & (CH - 1)], 1);
  __syncthreads();
  int deg = (tid < CH) ? hist[tid] : 0;
  sc[tid] = deg;
  __syncthreads();
  for (int off = 1; off < 256; off <<= 1) {
    int val = (tid >= off) ? sc[tid - off] : 0;
    __syncthreads();
    sc[tid] += val;
    __syncthreads();
  }
  int excl = sc[tid] - deg;
  int node = c * CH + tid;
  if (tid < CH) {
    lrun[tid] = excl;
    if (node < NN) {
      float dv = rsqrtf((float)(deg + 1));  // in-degree + self loop
      rowptr[node] = e0 + excl;
      dinv[node] = dv;
      ldv[tid] = dv;
    } else if (node == NN) {
      rowptr[NN] = e0 + excl;  // == NE (last chunk)
    }
  }
  __syncthreads();
  for (int i = tid; i < nv; i += 256) {
    int2 r = erec[e0 + i];
    int ln = r.y & (CH - 1);
    int pos = atomicAdd(&lrun[ln], 1);
    esrc[e0 + pos] = r.x;
    ew[e0 + pos] = ldv[ln];
  }
}

// ---------------- MFMA GEMM1: xw1'[n] = dinv[n]*(x[n] @ W1), fp8 out ----------------
// fp8 row layout: ushort at pos t holds features (t, t+64); in C-layout these are
// cols nc*16+m and (nc+4)*16+m -- SAME lane, so packing is lane-local.

__global__ __launch_bounds__(256) void k_gemm_mfma(const float* __restrict__ A,
                                                   const unsigned short* __restrict__ Bp,
                                                   const float* __restrict__ dinv,
                                                   unsigned short* __restrict__ C) {
  constexpr int K = 128;
  constexpr int NCH = KF / 16;
  const int wv = blockIdx.x * 4 + (threadIdx.x >> 6);
  const int row0 = wv * 16;
  if (row0 >= NN) return;  // 100000 % 16 == 0
  const int lane = threadIdx.x & 63;
  const int m = lane & 15;
  const int q = lane >> 4;

  floatx4 acc[NCH];
#pragma unroll
  for (int i = 0; i < NCH; ++i) acc[i] = (floatx4){0.f, 0.f, 0.f, 0.f};

  const int arow = row0 + m;
#pragma unroll
  for (int kc = 0; kc < 4; ++kc) {
    const float* ap = A + (size_t)arow * K + kc * 32 + q * 8;
    float4 f0 = *(const float4*)ap;
    float4 f1 = *(const float4*)(ap + 4);
    short8 af;
    af[0] = (short)f2bf(f0.x); af[1] = (short)f2bf(f0.y);
    af[2] = (short)f2bf(f0.z); af[3] = (short)f2bf(f0.w);
    af[4] = (short)f2bf(f1.x); af[5] = (short)f2bf(f1.y);
    af[6] = (short)f2bf(f1.z); af[7] = (short)f2bf(f1.w);
    const unsigned short* bp = Bp + (size_t)kc * NCH * 512;
#pragma unroll
    for (int nc = 0; nc < NCH; ++nc) {
      short8 bfr = *(const short8*)(bp + (size_t)nc * 512 + lane * 8);
      acc[nc] = __builtin_amdgcn_mfma_f32_16x16x32_bf16(af, bfr, acc[nc], 0, 0, 0);
    }
  }

  float ds[4];
#pragma unroll
  for (int r = 0; r < 4; ++r) ds[r] = dinv[row0 + q * 4 + r];
#pragma unroll
  for (int nc = 0; nc < 4; ++nc) {
#pragma unroll
    for (int r = 0; r < 4; ++r) {
      int row = row0 + q * 4 + r;
      C[(size_t)row * 64 + nc * 16 + m] =
          pk_fp8(acc[nc][r] * ds[r], acc[nc + 4][r] * ds[r]);
    }
  }
}

// ---------------- aggregation pass 1: paired-edge dword gathers (round-1 form) ----------------
// Row = 128 B = 32 dwords. Lanes 0-31 process even-offset edges, lanes 32-63
// odd-offset edges; each lane loads one dword = fp8 pairs for features
// (2u, 2u+64) and (2u+1, 2u+65). Halves fold via __shfl_down(.,32).
// h1'[n] = dinv[n]*relu( dinv[n]*(sum + self) + b1 ), fp8 out

__global__ __launch_bounds__(128) void k_agg1(const unsigned short* __restrict__ p,
                                              const float* __restrict__ bias,
                                              const int* __restrict__ rowptr,
                                              const int* __restrict__ esrc,
                                              const float* __restrict__ dinv,
                                              unsigned short* __restrict__ outp) {
  const int n = blockIdx.x * 2 + (threadIdx.x >> 6);
  const int t = threadIdx.x & 63;
  const int u = t & 31;      // dword index within the 32-dword row
  const int half = t >> 5;   // which edge of the pair this lane serves
  const unsigned* __restrict__ prow = (const unsigned*)p;

  // accumulators for features 2u, 2u+64, 2u+1, 2u+65
  float a0 = 0.f, a1 = 0.f, a2 = 0.f, a3 = 0.f;

  if (half == 0) {  // self term (prescaled input), added once
    unsigned v = prow[((unsigned)n << 5) + u];
    floatx2 lo = unpk_fp8((unsigned short)(v & 0xffffu));
    floatx2 hi = unpk_fp8((unsigned short)(v >> 16));
    a0 = lo.x; a1 = lo.y; a2 = hi.x; a3 = hi.y;
  }

  const int r0 = rowptr[n];
  const int r1 = rowptr[n + 1];
  int i = r0;

#define PAIR_TIER(NP)                                                  \
  for (; i + 2 * (NP) <= r1; i += 2 * (NP)) {                          \
    const int ib = i + half;                                           \
    unsigned s[NP];                                                    \
    _Pragma("unroll") for (int j = 0; j < (NP); ++j)                   \
        s[j] = (unsigned)esrc[ib + 2 * j];                             \
    unsigned v[NP];                                                    \
    _Pragma("unroll") for (int j = 0; j < (NP); ++j)                   \
        v[j] = prow[(s[j] << 5) + u];                                  \
    _Pragma("unroll") for (int j = 0; j < (NP); ++j) {                 \
      floatx2 lo = unpk_fp8((unsigned short)(v[j] & 0xffffu));         \
      floatx2 hi = unpk_fp8((unsigned short)(v[j] >> 16));             \
      a0 += lo.x; a1 += lo.y; a2 += hi.x; a3 += hi.y;                  \
    }                                                                  \
  }

  PAIR_TIER(8)   // 16 edges / iter
  PAIR_TIER(4)   // 8
  PAIR_TIER(2)   // 4
  PAIR_TIER(1)   // 2
#undef PAIR_TIER

  if (i < r1 && half == 0) {  // odd leftover edge: half 0 only
    unsigned s = (unsigned)esrc[i];
    unsigned v = prow[(s << 5) + u];
    floatx2 lo = unpk_fp8((unsigned short)(v & 0xffffu));
    floatx2 hi = unpk_fp8((unsigned short)(v >> 16));
    a0 += lo.x; a1 += lo.y; a2 += hi.x; a3 += hi.y;
  }

  // fold half-wave partials: lane u gets lane u+32's sums
  a0 += __shfl_down(a0, 32, 64);
  a1 += __shfl_down(a1, 32, 64);
  a2 += __shfl_down(a2, 32, 64);
  a3 += __shfl_down(a3, 32, 64);

  if (half == 0) {
    const float dn = dinv[n];
    float2 blo = *(const float2*)(bias + 2 * u);       // bias[2u], bias[2u+1]
    float2 bhi = *(const float2*)(bias + 64 + 2 * u);  // bias[2u+64], bias[2u+65]
    float x0 = fmaxf(fmaf(dn, a0, blo.x), 0.f) * dn;   // feat 2u
    float x1 = fmaxf(fmaf(dn, a1, bhi.x), 0.f) * dn;   // feat 2u+64
    float x2 = fmaxf(fmaf(dn, a2, blo.y), 0.f) * dn;   // feat 2u+1
    float x3 = fmaxf(fmaf(dn, a3, bhi.y), 0.f) * dn;   // feat 2u+65
    unsigned lo = pk_fp8(x0, x1);
    unsigned hi = pk_fp8(x2, x3);
    ((unsigned*)outp)[((unsigned)n << 5) + u] = lo | (hi << 16);
  }
}

// ---------------- fused conv2 + partial mean-pool (NSPLIT blocks per graph) ----------------
// Graph g's nodes are contiguous [start,end); its CSR-by-dst edges are the
// contiguous flat range [rowptr[start], rowptr[end]). Block (g, part) handles a
// 1/NSPLIT slice of both, accumulates a 128-float partial pooled sum, then
// atomicAdds it into pooled[g][.]. Grid = NGR*NSPLIT = 4096 blocks.
// Inner loop unrolled 8x (matching k_agg1's PAIR_TIER(8) MLP: 8 row-gathers in
// flight per lane); 4 waves x 2 edges = stride 8, so a lane covers i..i+56.

__global__ __launch_bounds__(256) void k_aggpart(const unsigned short* __restrict__ p,
                                                 const int* __restrict__ batch,
                                                 const int* __restrict__ rowptr,
                                                 const int* __restrict__ esrc,
                                                 const float* __restrict__ ew,
                                                 const float* __restrict__ dinv,
                                                 float* __restrict__ pooled) {
  __shared__ float sacc[4][128];
  __shared__ int bnd[2];
  const int g = blockIdx.x / NSPLIT;
  const int part = blockIdx.x % NSPLIT;
  const int tid = threadIdx.x;
  if (tid < 2) {
    int target = g + tid;
    int lo = 0, hi = NN;
    while (lo < hi) { int mid = (lo + hi) >> 1; if (batch[mid] < target) lo = mid + 1; else hi = mid; }
    bnd[tid] = lo;
  }
  __syncthreads();
  const int start = bnd[0], end = bnd[1];
  const int wv = tid >> 6, t = tid & 63, u = t & 31, half = t >> 5;
  const unsigned* __restrict__ prow = (const unsigned*)p;

  float a0 = 0.f, a1 = 0.f, a2 = 0.f, a3 = 0.f;

  // edge slice
  const int e0 = rowptr[start];
  const int e1 = rowptr[end];  // rowptr[NN] == NE
  const int elen = e1 - e0;
  const int eper = (elen + NSPLIT - 1) / NSPLIT;
  const int is = min(e0 + part * eper, e1);
  const int ie = min(is + eper, e1);

  int i = is + wv * 2 + half;
  // 8x unrolled: lane's edges are i, i+8, ..., i+56 (4 waves x 2 edges = stride 8)
  for (; i + 56 < ie; i += 64) {
    unsigned s[8];
    float w[8];
    unsigned v[8];
#pragma unroll
    for (int j = 0; j < 8; ++j) s[j] = (unsigned)esrc[i + 8 * j];
#pragma unroll
    for (int j = 0; j < 8; ++j) w[j] = ew[i + 8 * j];
#pragma unroll
    for (int j = 0; j < 8; ++j) v[j] = prow[(s[j] << 5) + u];
#pragma unroll
    for (int j = 0; j < 8; ++j) {
      floatx2 lo = unpk_fp8((unsigned short)(v[j] & 0xffffu));
      floatx2 hi = unpk_fp8((unsigned short)(v[j] >> 16));
      a0 = fmaf(w[j], lo.x, a0); a1 = fmaf(w[j], lo.y, a1);
      a2 = fmaf(w[j], hi.x, a2); a3 = fmaf(w[j], hi.y, a3);
    }
  }
  for (; i < ie; i += 8) {
    unsigned s_ = (unsigned)esrc[i];
    float w_ = ew[i];
    unsigned v_ = prow[(s_ << 5) + u];
    floatx2 lo = unpk_fp8((unsigned short)(v_ & 0xffffu));
    floatx2 hi = unpk_fp8((unsigned short)(v_ >> 16));
    a0 = fmaf(w_, lo.x, a0); a1 = fmaf(w_, lo.y, a1);
    a2 = fmaf(w_, hi.x, a2); a3 = fmaf(w_, hi.y, a3);
  }

  // self-node slice: weight dinv[n]
  const int nlen = end - start;
  const int nper = (nlen + NSPLIT - 1) / NSPLIT;
  const int ns = min(start + part * nper, end);
  const int ne = min(ns + nper, end);
  for (int n = ns + wv * 2 + half; n < ne; n += 8) {
    float w_ = dinv[n];
    unsigned v_ = prow[((unsigned)n << 5) + u];
    floatx2 lo = unpk_fp8((unsigned short)(v_ & 0xffffu));
    floatx2 hi = unpk_fp8((unsigned short)(v_ >> 16));
    a0 = fmaf(w_, lo.x, a0); a1 = fmaf(w_, lo.y, a1);
    a2 = fmaf(w_, hi.x, a2); a3 = fmaf(w_, hi.y, a3);
  }

  // fold the two half-wave edge streams
  a0 += __shfl_down(a0, 32, 64);
  a1 += __shfl_down(a1, 32, 64);
  a2 += __shfl_down(a2, 32, 64);
  a3 += __shfl_down(a3, 32, 64);
  if (half == 0) {
    sacc[wv][2 * u] = a0;       // feat 2u
    sacc[wv][2 * u + 1] = a2;   // feat 2u+1
    sacc[wv][2 * u + 64] = a1;  // feat 2u+64
    sacc[wv][2 * u + 65] = a3;  // feat 2u+65
  }
  __syncthreads();
  if (tid < KF) {
    float v = sacc[0][tid] + sacc[1][tid] + sacc[2][tid] + sacc[3][tid];
    atomicAdd(&pooled[(size_t)g * KF + tid], v);
  }
}

// ---------------- heads: mean + W2 GEMM + group/family heads (one block per graph) -------------

__global__ __launch_bounds__(256) void k_heads(const float* __restrict__ pooled,
                                               const int* __restrict__ batch,
                                               const float* __restrict__ W2,
                                               const float* __restrict__ b2,
                                               const float* __restrict__ Wg,
                                               const float* __restrict__ bg,
                                               const float* __restrict__ Wf,
                                               const float* __restrict__ bfb,
                                               float* __restrict__ out) {
  __shared__ float pr[KF];
  __shared__ float pp[H2F];
  __shared__ int bnd[2];
  const int g = blockIdx.x;
  const int tid = threadIdx.x;
  if (tid < 2) {
    int target = g + tid;
    int lo = 0, hi = NN;
    while (lo < hi) { int mid = (lo + hi) >> 1; if (batch[mid] < target) lo = mid + 1; else hi = mid; }
    bnd[tid] = lo;
  }
  __syncthreads();
  if (tid < KF) {
    float c = fmaxf((float)(bnd[1] - bnd[0]), 1.f);
    pr[tid] = pooled[(size_t)g * KF + tid] / c;
  }
  __syncthreads();
  float acc = b2[tid];
#pragma unroll 8
  for (int d = 0; d < KF; ++d) acc = fmaf(pr[d], W2[d * H2F + tid], acc);
  pp[tid] = acc;
  __syncthreads();
  if (tid < NGRP) {
    float a = bg[tid];
    for (int d = 0; d < H2F; ++d) a = fmaf(pp[d], Wg[d * NGRP + tid], a);
    out[g * NGRP + tid] = a;
  } else if (tid >= 64 && tid < 64 + NGRP * NFAM) {
    int uu = tid - 64;
    int gg = uu / NFAM;
    int ff = uu % NFAM;
    float a = bfb[gg * NFAM + ff];
    for (int d = 0; d < H2F; ++d) a = fmaf(pp[d], Wf[(gg * H2F + d) * NFAM + ff], a);
    out[NGR * NGRP + (size_t)gg * NGR * NFAM + g * NFAM + ff] = a;
  }
}

// ---------------- launch ----------------

extern "C" void kernel_launch(void* const* d_in, const int* in_sizes, int n_in,
                              void* d_out, int out_size, void* d_ws, size_t ws_size,
                              hipStream_t stream) {
  const float* x    = (const float*)d_in[0];
  const int*   ei   = (const int*)d_in[1];
  const int*   batch= (const int*)d_in[2];
  const float* W1   = (const float*)d_in[3];
  const float* b1   = (const float*)d_in[4];
  const float* W2   = (const float*)d_in[5];
  const float* b2   = (const float*)d_in[6];
  const float* Wg   = (const float*)d_in[7];
  const float* bg   = (const float*)d_in[8];
  const float* Wf   = (const float*)d_in[9];
  const float* bfb  = (const float*)d_in[10];
  float* out = (float*)d_out;

  char* w = (char*)d_ws;
  auto take = [&](size_t bytes) {
    char* p = w;
    w += (bytes + 255) & ~(size_t)255;
    return (void*)p;
  };
  int*   tot   = (int*)take((size_t)NCHUNK * 4);
  float* pooled= (float*)take((size_t)NGR * KF * 4);  // adjacent to tot: one memset covers both
  int*   cbase = (int*)take((size_t)(NCHUNK + 1) * 4);
  int*   cursor= (int*)take((size_t)NCHUNK * 4);
  int2*  erec  = (int2*)take((size_t)NE * 8);
  int*   esrc  = (int*)take((size_t)NE * 4);
  float* ew    = (float*)take((size_t)NE * 4);
  int*   rowptr= (int*)take((size_t)(NN + 1) * 4);
  float* dinv  = (float*)take((size_t)NN * 4);
  unsigned short* Bp1 = (unsigned short*)take((size_t)KF * KF * 2);
  unsigned short* xw1 = (unsigned short*)take((size_t)NN * 64 * 2);  // fp8 pairs
  unsigned short* h1  = (unsigned short*)take((size_t)NN * 64 * 2);  // fp8 pairs

  // zero tot + pooled in one shot (adjacent in workspace)
  size_t zbytes = (size_t)((char*)pooled - (char*)tot) + (size_t)NGR * KF * 4;
  hipMemsetAsync(tot, 0, zbytes, stream);

  k_histprep<<<NT + PREPB_BLKS, 256, 0, stream>>>(ei, tot, W1, Bp1);
  k_scantot<<<1, 256, 0, stream>>>(tot, cbase, cursor);
  k_pscatter<<<NT, 256, 0, stream>>>(ei, cursor, erec);
  k_sort<<<NCHUNK, 256, 0, stream>>>(erec, cbase, esrc, ew, rowptr, dinv);

  k_gemm_mfma<<<1563, 256, 0, stream>>>(x, Bp1, dinv, xw1);

  k_agg1<<<NN / 2, 128, 0, stream>>>(xw1, b1, rowptr, esrc, dinv, h1);
  k_aggpart<<<NGR * NSPLIT, 256, 0, stream>>>(h1, batch, rowptr, esrc, ew, dinv, pooled);
  k_heads<<<NGR, 256, 0, stream>>>(pooled, batch, W2, b2, Wg, bg, Wf, bfb, out);
}